// Round 4
// baseline (200.524 us; speedup 1.0000x reference)
//
#include <hip/hip_runtime.h>

#define CAND_CAP 320
#define TMP_CAP 64
#define M_MAX 1024
#define FTMP_CAP 128
#define NBIN 3584   // 15^3 = 3375 cells, padded to 256*14

typedef __attribute__((ext_vector_type(8))) short bf16x8;
typedef __attribute__((ext_vector_type(4))) float f32x4;
typedef __attribute__((ext_vector_type(2))) float f32x2;

__device__ __forceinline__ unsigned short f2bf(float x) {
  unsigned u = __float_as_uint(x);
  unsigned r = (u + 0x7fffu + ((u >> 16) & 1u)) >> 16;
  return (unsigned short)r;
}

__device__ __forceinline__ int cell15(float x, float y, float z) {
  int cx = min((int)(x * 15.0f), 14);
  int cy = min((int)(y * 15.0f), 14);
  int cz = min((int)(z * 15.0f), 14);
  return (cz * 15 + cy) * 15 + cx;
}

// ============================ fused prep kernel ============================
__global__ __launch_bounds__(256) void prep_kernel(
    const float* __restrict__ g, const float* __restrict__ s, const float* __restrict__ v,
    const float* __restrict__ W2, unsigned short* __restrict__ W2F,
    int* __restrict__ starts, float4* __restrict__ binned) {
  const int b = blockIdx.x;
  if (b < 3) {
    __shared__ int hist[NBIN];
    __shared__ int wsum[4];
    const int tid = threadIdx.x, lane = tid & 63, wv = tid >> 6;
    const float* p = (b == 0) ? g : (b == 1) ? s : v;
    const int Np = (b == 2) ? 8192 : 4096;
    const int base = (b == 0) ? 0 : (b == 1) ? 4096 : 8192;

    for (int i = tid; i < NBIN; i += 256) hist[i] = 0;
    __syncthreads();
    for (int i = tid; i < Np; i += 256) {
      float x = p[i * 3 + 0], y = p[i * 3 + 1], z = p[i * 3 + 2];
      atomicAdd(&hist[cell15(x, y, z)], 1);
    }
    __syncthreads();
    // per-thread 14-bin local prefix, then wave+block scan of totals
    int loc[14];
    int run = 0;
#pragma unroll
    for (int k = 0; k < 14; ++k) { loc[k] = run; run += hist[tid * 14 + k]; }
    int is = run;
#pragma unroll
    for (int o = 1; o < 64; o <<= 1) {
      int t = __shfl_up(is, o, 64);
      if (lane >= o) is += t;
    }
    if (lane == 63) wsum[wv] = is;
    __syncthreads();
    int off = is - run;
    for (int w = 0; w < wv; ++w) off += wsum[w];
#pragma unroll
    for (int k = 0; k < 14; ++k) {
      int e = off + loc[k];
      hist[tid * 14 + k] = e;
      starts[b * NBIN + tid * 14 + k] = e;  // pad bins >= 3375 get Np (sentinel)
    }
    __syncthreads();
    for (int i = tid; i < Np; i += 256) {
      float x = p[i * 3 + 0], y = p[i * 3 + 1], z = p[i * 3 + 2];
      int pos = atomicAdd(&hist[cell15(x, y, z)], 1);
      binned[base + pos] = make_float4(x, y, z, __int_as_float(i));
    }
  } else {
    int t = (b - 3) * 256 + threadIdx.x;
    int s_ = t >> 13;
    int rem = t & 8191;
    int nb = rem >> 9;
    int rem2 = rem & 511;
    int kt = rem2 >> 6;
    int l = rem2 & 63;
    int n = nb * 16 + (l & 15);
    int k0 = kt * 32 + (l >> 4) * 8;
    bf16x8 vfr;
#pragma unroll
    for (int j = 0; j < 8; ++j)
      vfr[j] = (short)f2bf(W2[((size_t)s_ * 256 + (k0 + j)) * 256 + n]);
    *(bf16x8*)(W2F + (size_t)t * 8) = vfr;
  }
}

// ============================ merged select kernel ============================
struct SelDesc {
  const float* qptr[7];
  int pbase[7];
  int soff[7];
  int w1off[7];
  int b1off[7];
  int foff[7];
  float r1[7];
  int blkstart[8];
};

__global__ __launch_bounds__(256, 8) void bq_select_grid(
    SelDesc d, const float* __restrict__ W1all, const float* __restrict__ b1all,
    const float4* __restrict__ binned, const int* __restrict__ starts,
    unsigned short* __restrict__ fbuf) {
  __shared__ unsigned long long keys[4][CAND_CAP];   // 10240 B
  __shared__ unsigned long long tmpb[4][2][TMP_CAP]; // 4096 B
  __shared__ unsigned long long Tkey[4][2];          // 64 B
  __shared__ int hist64[4][64];                      // 1024 B
  __shared__ int bbin[4][2];                         // 32 B
  __shared__ int msel[4][2];                         // 32 B
  __shared__ float4 sel[4][32];                      // 2048 B
  __shared__ float4 sel16[4][16];                    // 1024 B  -> 18560 B total

  const int tid = threadIdx.x, lane = tid & 63, wv = tid >> 6;

  int st = 0;
  while ((int)blockIdx.x >= d.blkstart[st + 1]) ++st;
  const int qlocal = ((int)blockIdx.x - d.blkstart[st]) * 4 + wv;
  const float* qpts = d.qptr[st];
  const int pbase = d.pbase[st];
  const int soff = d.soff[st];

  if (lane == 0) {
    Tkey[wv][0] = 0; Tkey[wv][1] = 0;
    bbin[wv][0] = -1; bbin[wv][1] = -1;
    msel[wv][0] = 0; msel[wv][1] = 0;
  }
  const float qx = qpts[qlocal * 3 + 0];
  const float qy = qpts[qlocal * 3 + 1];
  const float qz = qpts[qlocal * 3 + 2];

  // ---- adaptive phase-1 radius: keep E[candidates] ~constant near boundaries ----
  // Exactness: if count(d2 <= rr^2) >= 32 then top-32 of that set == global top-32
  // (everything unscanned is farther). rr >= 0.1 always => scale-0 exact from phase 1.
  float rr = d.r1[st];
  {
    float inv2r = 0.5f / rr;
    float fx = (fminf(qx + rr, 1.0f) - fmaxf(qx - rr, 0.0f)) * inv2r;
    float fy = (fminf(qy + rr, 1.0f) - fmaxf(qy - rr, 0.0f)) * inv2r;
    float fz = (fminf(qz + rr, 1.0f) - fmaxf(qz - rr, 0.0f)) * inv2r;
    rr = fminf(0.2f, 1.03f * rr / cbrtf(fx * fy * fz));
  }
  float rrsq = fminf(rr * rr, 0.04f);

  int cnt = 0;
  for (int phase = 0;; ++phase) {
    hist64[wv][lane] = 0;
    __builtin_amdgcn_wave_barrier();
    __threadfence_block();

    // ---- register row table (per-row x-chord culling), 15^3 grid ----
    int T, rs_reg, ra_reg;
    {
      const int cy0 = max(0, (int)floorf((qy - rr) * 15.0f));
      const int cy1 = min(14, (int)floorf((qy + rr) * 15.0f));
      const int cz0 = max(0, (int)floorf((qz - rr) * 15.0f));
      const int cz1 = min(14, (int)floorf((qz + rr) * 15.0f));
      const int ncy = cy1 - cy0 + 1;
      const int nrows = (cz1 - cz0 + 1) * ncy;   // <= 49 at rr=0.2
      // magic-mul replaces per-lane integer division lane/ncy (exact for lane<64, ncy<=7)
      const int magic = (ncy == 1) ? 256 : (ncy == 2) ? 128 : (ncy == 3) ? 86 :
                        (ncy == 4) ? 64  : (ncy == 5) ? 52  : (ncy == 6) ? 43 : 37;
      int len = 0, beg = 0;
      if (lane < nrows) {
        int czi = (lane * magic) >> 8;
        int cz = cz0 + czi;
        int cy = cy0 + (lane - czi * ncy);
        const float CS = 1.0f / 15.0f;
        float lo = cz * CS;
        float dz = fmaxf(fmaxf(lo - qz, qz - (lo + CS)), 0.0f);
        float loy = cy * CS;
        float dy = fmaxf(fmaxf(loy - qy, qy - (loy + CS)), 0.0f);
        float dyz2 = dz * dz + dy * dy;
        if (dyz2 <= rrsq) {
          float xr = __builtin_sqrtf(rrsq - dyz2);
          int cxlo = max(0, (int)floorf((qx - xr) * 15.0f));
          int cxhi = min(14, (int)floorf((qx + xr) * 15.0f));
          int rowb = (cz * 15 + cy) * 15;
          beg = starts[soff + rowb + cxlo];
          int end = starts[soff + rowb + cxhi + 1];
          len = end - beg;
        }
      }
      int incl = len;
#pragma unroll
      for (int o = 1; o < 64; o <<= 1) {
        int t = __shfl_up(incl, o, 64);
        if (lane >= o) incl += t;
      }
      T = __shfl(incl, 63, 64);
      rs_reg = incl - len;          // exclusive prefix; lanes >= nrows hold T
      ra_reg = beg - rs_reg;
    }

    // ---- dense scan: 4 sub-chunks batched for ILP (independent bsearch chains,
    // all 4 gathers issued before processing) ----
    cnt = 0;
    for (int jb = 0; jb < T; jb += 256) {
      int jj[4], rw[4], sl[4];
      float4 PP[4];
#pragma unroll
      for (int c = 0; c < 4; ++c) { jj[c] = jb + (c << 6) + lane; rw[c] = 0; }
#pragma unroll
      for (int stp = 32; stp >= 1; stp >>= 1) {
#pragma unroll
        for (int c = 0; c < 4; ++c) {
          int cc = rw[c] + stp;                  // <= 63 always
          int val = __shfl(rs_reg, cc, 64);
          if (val <= jj[c]) rw[c] = cc;
        }
      }
#pragma unroll
      for (int c = 0; c < 4; ++c) {
        int sl_ = pbase + jj[c] + __shfl(ra_reg, rw[c], 64);
        sl[c] = (jj[c] < T) ? sl_ : pbase;       // clamp dead lanes to a safe slot
      }
#pragma unroll
      for (int c = 0; c < 4; ++c) PP[c] = binned[sl[c]];
#pragma unroll
      for (int c = 0; c < 4; ++c) {
        float dx = PP[c].x - qx, dyy = PP[c].y - qy, dzz = PP[c].z - qz;
        float d2 = dx * dx + dyy * dyy + dzz * dzz;
        bool pred = (jj[c] < T) && (d2 <= rrsq);
        unsigned long long mask = __ballot(pred);
        if (pred) {
          int mypos = cnt + __popcll(mask & ((1ull << lane) - 1ull));
          if (mypos < CAND_CAP)
            keys[wv][mypos] = ((unsigned long long)__float_as_uint(d2) << 32) |
                              (unsigned)sl[c];
          atomicAdd(&hist64[wv][min((int)(d2 * 1600.0f), 63)], 1);
        }
        cnt += __popcll(mask);
      }
    }
    if (cnt >= 32 || phase == 1 || rr >= 0.2f) break;
    rr = 0.2f; rrsq = 0.04f;   // rare retry (~0.3-2%): sparse neighborhood
  }
  __builtin_amdgcn_wave_barrier();
  __threadfence_block();
  const int cntf = min(cnt, CAND_CAP);
  const bool need32 = cnt > 32;

  // ---- hist64 prefix scan: c16 = sum bins<16 (= #d2<0.01); boundary bins ----
  int c16;
  {
    int h = hist64[wv][lane];
    int incl = h;
#pragma unroll
    for (int o = 1; o < 64; o <<= 1) {
      int t = __shfl_up(incl, o, 64);
      if (lane >= o) incl += t;
    }
    int excl = incl - h;
    c16 = __shfl(excl, 16, 64);    // exclusive prefix at bin 16 (d2 < 0.01)
    const bool n16b = c16 > 16;
    if (need32 && incl >= 32 && excl < 32) { bbin[wv][1] = lane; msel[wv][1] = 32 - excl; }
    if (n16b   && incl >= 16 && excl < 16) { bbin[wv][0] = lane; msel[wv][0] = 16 - excl; }
  }
  __builtin_amdgcn_wave_barrier();
  __threadfence_block();
  const int k16 = min(16, c16);
  const bool need16 = c16 > 16;
  const int b32b = bbin[wv][1];
  const int b16b = bbin[wv][0];

  // ---- collect boundary-bin keys (ballot compaction, only needed scales) ----
  int t32c = 0, t16c = 0;
  if (need32 | need16) {
    for (int base = 0; base < cntf; base += 64) {
      int i = base + lane;
      bool in = i < cntf;
      unsigned long long key = in ? keys[wv][i] : 0xFFFFFFFFFFFFFFFFull;
      float d2 = __uint_as_float((unsigned)(key >> 32));
      int bb = min((int)(d2 * 1600.0f), 63);
      if (need32) {
        bool p1 = in && (bb == b32b);
        unsigned long long m1 = __ballot(p1);
        if (p1) {
          int pos = t32c + __popcll(m1 & ((1ull << lane) - 1ull));
          if (pos < TMP_CAP) tmpb[wv][1][pos] = key;
        }
        t32c += __popcll(m1);
      }
      if (need16) {
        bool p0 = in && (bb == b16b);
        unsigned long long m0 = __ballot(p0);
        if (p0) {
          int pos = t16c + __popcll(m0 & ((1ull << lane) - 1ull));
          if (pos < TMP_CAP) tmpb[wv][0][pos] = key;
        }
        t16c += __popcll(m0);
      }
    }
  }
  __builtin_amdgcn_wave_barrier();
  __threadfence_block();

  // ---- rank-select m-th smallest key in each needed boundary bin ----
#pragma unroll
  for (int s = 0; s < 2; ++s) {
    const bool nd = s ? need32 : need16;
    if (nd) {
      const int h = min(s ? t32c : t16c, TMP_CAP);
      const int m = msel[wv][s];
      if (lane < h) {
        unsigned long long e = tmpb[wv][s][lane];
        int less = 0;
        for (int j = 0; j < h; ++j) less += (tmpb[wv][s][j] < e) ? 1 : 0;
        if (less == m - 1) Tkey[wv][s] = e;
      }
    }
  }
  __builtin_amdgcn_wave_barrier();
  __threadfence_block();
  const unsigned long long T32 =
      need32 ? Tkey[wv][1] : 0xFFFFFFFFFFFFFFFFull;
  const unsigned long long T16 =
      need16 ? Tkey[wv][0]
             : (((unsigned long long)__float_as_uint(0.01f) << 32) | 0xFFFFFFFFull);

  // ---- compact selected neighbors (ballot); coords via one binned[] load ----
  int sc = 0, sc16 = 0;
  for (int base = 0; base < cntf; base += 64) {
    int i = base + lane;
    bool in = i < cntf;
    unsigned long long key = in ? keys[wv][i] : 0xFFFFFFFFFFFFFFFFull;
    bool pred = in && (key <= T32);
    bool pred16 = in && (key <= T16);
    unsigned long long mask = __ballot(pred);
    unsigned long long mask16 = __ballot(pred16);
    unsigned long long lt = (1ull << lane) - 1ull;
    if (pred) {
      int pos = sc + __popcll(mask & lt);
      if (pos < 32) {
        float4 P = binned[key & 0xffffffffu];
        float rx = P.x - qx;
        float ry = P.y - qy;
        float rz = P.z - qz;
        sel[wv][pos] = make_float4(rx, ry, rz, 0.0f);
        if (pred16) {
          int p16 = sc16 + __popcll(mask16 & lt);
          if (p16 < 16) sel16[wv][p16] = make_float4(rx, ry, rz, 0.0f);
        }
      }
    }
    sc += __popcll(mask);
    sc16 += __popcll(mask16);
  }
  __builtin_amdgcn_wave_barrier();
  __threadfence_block();
  const int nsel = min(sc, 32);
  const int n16 = min(sc16, 16);

  // ---- dual max-pool, 2-neighbor unroll (fmax(fmax) -> v_max3) ----
  {
    const float* W1 = W1all + d.w1off[st];
    const float* b1 = b1all + d.b1off[st];
    const int c0 = lane * 2;
    const f32x2 wx0 = *(const f32x2*)(W1 + 0 * 128 + c0);
    const f32x2 wy0 = *(const f32x2*)(W1 + 1 * 128 + c0);
    const f32x2 wz0 = *(const f32x2*)(W1 + 2 * 128 + c0);
    const f32x2 wx1 = *(const f32x2*)(W1 + 384 + 0 * 128 + c0);
    const f32x2 wy1 = *(const f32x2*)(W1 + 384 + 1 * 128 + c0);
    const f32x2 wz1 = *(const f32x2*)(W1 + 384 + 2 * 128 + c0);
    const f32x2 bb0 = *(const f32x2*)(b1 + c0);
    const f32x2 bb1 = *(const f32x2*)(b1 + 128 + c0);
    f32x2 m0; m0.x = -INFINITY; m0.y = -INFINITY;
    f32x2 m1 = m0;
    int n = 0;
    for (; n + 2 <= n16; n += 2) {
      float4 e0 = sel16[wv][n];
      float4 e1 = sel16[wv][n + 1];
      f32x2 v0 = e0.x * wx0 + e0.y * wy0 + e0.z * wz0;
      f32x2 v1 = e1.x * wx0 + e1.y * wy0 + e1.z * wz0;
      m0.x = fmaxf(m0.x, fmaxf(v0.x, v1.x));
      m0.y = fmaxf(m0.y, fmaxf(v0.y, v1.y));
    }
    if (n < n16) {
      float4 e = sel16[wv][n];
      f32x2 v = e.x * wx0 + e.y * wy0 + e.z * wz0;
      m0.x = fmaxf(m0.x, v.x);
      m0.y = fmaxf(m0.y, v.y);
    }
    n = 0;
    for (; n + 2 <= nsel; n += 2) {
      float4 e0 = sel[wv][n];
      float4 e1 = sel[wv][n + 1];
      f32x2 v0 = e0.x * wx1 + e0.y * wy1 + e0.z * wz1;
      f32x2 v1 = e1.x * wx1 + e1.y * wy1 + e1.z * wz1;
      m1.x = fmaxf(m1.x, fmaxf(v0.x, v1.x));
      m1.y = fmaxf(m1.y, fmaxf(v0.y, v1.y));
    }
    if (n < nsel) {
      float4 e = sel[wv][n];
      f32x2 v = e.x * wx1 + e.y * wy1 + e.z * wz1;
      m1.x = fmaxf(m1.x, v.x);
      m1.y = fmaxf(m1.y, v.y);
    }
    ushort2 o0, o1;
    o0.x = f2bf(fmaxf(m0.x + bb0.x, 0.0f));
    o0.y = f2bf(fmaxf(m0.y + bb0.y, 0.0f));
    o1.x = f2bf(fmaxf(m1.x + bb1.x, 0.0f));
    o1.y = f2bf(fmaxf(m1.y + bb1.y, 0.0f));
    unsigned short* fr = fbuf + (size_t)(d.foff[st] + qlocal) * 256;
    *(ushort2*)(fr + c0) = o0;
    *(ushort2*)(fr + 128 + c0) = o1;
  }
}

// ============================ MFMA GEMM kernel ============================
struct GemmDesc {
  const float* basep[3];
  float* outp[3];
  int blkstart[4];
  int nst[3];
  int foff[3][3];
  int w2off[3][3];
  int b2off[3][3];
};

__global__ __launch_bounds__(256) void bq_gemm_mfma(
    GemmDesc d, const unsigned short* __restrict__ W2F,
    const float* __restrict__ b2all, const unsigned short* __restrict__ fbuf) {
  __shared__ unsigned short ftile[32][264];
  const int tid = threadIdx.x, lane = tid & 63, wv = tid >> 6;

  int rg = 0;
  while ((int)blockIdx.x >= d.blkstart[rg + 1]) ++rg;
  const int qb = ((int)blockIdx.x - d.blkstart[rg]) * 32;

  f32x4 acc[2][4];
#pragma unroll
  for (int mt = 0; mt < 2; ++mt)
#pragma unroll
    for (int nt = 0; nt < 4; ++nt) acc[mt][nt] = (f32x4)0.0f;

  const int nst = d.nst[rg];
  for (int s = 0; s < nst; ++s) {
    __syncthreads();
    {
      const unsigned short* fsrc = fbuf + (size_t)(d.foff[rg][s] + qb) * 256;
#pragma unroll
      for (int i = 0; i < 4; ++i) {
        int c = tid + 256 * i;
        int row = c >> 5, k8 = (c & 31) * 8;
        *(uint4*)&ftile[row][k8] = *(const uint4*)(fsrc + (size_t)row * 256 + k8);
      }
    }
    __syncthreads();
    const unsigned short* wbase = W2F + d.w2off[rg][s];
#pragma unroll
    for (int kt = 0; kt < 8; ++kt) {
      const int koff = kt * 32 + (lane >> 4) * 8;
      bf16x8 a0 = *(const bf16x8*)&ftile[lane & 15][koff];
      bf16x8 a1 = *(const bf16x8*)&ftile[16 + (lane & 15)][koff];
#pragma unroll
      for (int nt = 0; nt < 4; ++nt) {
        int nb = wv * 4 + nt;
        bf16x8 bfr = *(const bf16x8*)(wbase + (size_t)((nb * 8 + kt) * 64 + lane) * 8);
        acc[0][nt] = __builtin_amdgcn_mfma_f32_16x16x32_bf16(a0, bfr, acc[0][nt], 0, 0, 0);
        acc[1][nt] = __builtin_amdgcn_mfma_f32_16x16x32_bf16(a1, bfr, acc[1][nt], 0, 0, 0);
      }
    }
  }

  float bb[4];
#pragma unroll
  for (int nt = 0; nt < 4; ++nt) {
    int c = wv * 64 + nt * 16 + (lane & 15);
    float sum = 0.0f;
    for (int s = 0; s < nst; ++s) sum += b2all[d.b2off[rg][s] + c];
    bb[nt] = sum;
  }

  const float* __restrict__ basep = d.basep[rg];
  float* __restrict__ outp = d.outp[rg];
#pragma unroll
  for (int mt = 0; mt < 2; ++mt) {
#pragma unroll
    for (int r = 0; r < 4; ++r) {
      int q = qb + mt * 16 + (lane >> 4) * 4 + r;
#pragma unroll
      for (int nt = 0; nt < 4; ++nt) {
        int c = wv * 64 + nt * 16 + (lane & 15);
        outp[(size_t)q * 256 + c] = basep[(size_t)q * 256 + c] + acc[mt][nt][r] + bb[nt];
      }
    }
  }
}

// ============================ fused fallback (tiny ws) ============================
__global__ __launch_bounds__(256) void init_out_kernel(
    const float* __restrict__ g, const float* __restrict__ s, const float* __restrict__ v,
    float* __restrict__ out) {
  const int NG = 4096 * 256, NS = 4096 * 256;
  int i = blockIdx.x * 256 + threadIdx.x;
  if (i < NG) out[i] = g[i];
  else if (i < NG + NS) out[i] = s[i - NG];
  else out[i] = v[i - NG - NS];
}

__global__ __launch_bounds__(256) void bq_stack_fused(
    const float* __restrict__ qpts,
    const float* __restrict__ ppts, int Np,
    const float* __restrict__ W1, const float* __restrict__ b1,
    const float* __restrict__ W2, const float* __restrict__ b2,
    float* __restrict__ out) {
  __shared__ unsigned long long keys[M_MAX];
  __shared__ int hist32[256];
  __shared__ int hist16[64];
  __shared__ unsigned long long tmpb[2][FTMP_CAP];
  __shared__ int tmpcnt[2];
  __shared__ float4 sel[32];
  __shared__ int selcnt;
  __shared__ float f_lds[256];
  __shared__ int cnt_s;
  __shared__ unsigned long long T_lds[2];
  __shared__ int bbin[2], msel[2];
  __shared__ int wsum[4];
  __shared__ float qsh[3];

  const int tid = threadIdx.x;
  const int lane = tid & 63;
  const int wv = tid >> 6;
  const int q = blockIdx.x;

  hist32[tid] = 0;
  if (tid < 64) hist16[tid] = 0;
  if (tid == 0) {
    cnt_s = 0; selcnt = 0; tmpcnt[0] = 0; tmpcnt[1] = 0;
    T_lds[0] = ~0ULL; T_lds[1] = ~0ULL;
    qsh[0] = qpts[q * 3 + 0]; qsh[1] = qpts[q * 3 + 1]; qsh[2] = qpts[q * 3 + 2];
  }
  __syncthreads();
  const float qx = qsh[0], qy = qsh[1], qz = qsh[2];

  const float4* pp4 = (const float4*)ppts;
  const int groups = Np >> 2;
  for (int gp = tid; gp < groups; gp += 256) {
    float4 A = pp4[gp * 3 + 0];
    float4 Bv = pp4[gp * 3 + 1];
    float4 C = pp4[gp * 3 + 2];
    float px[4] = {A.x, A.w, Bv.z, C.y};
    float py[4] = {A.y, Bv.x, Bv.w, C.z};
    float pz[4] = {A.z, Bv.y, C.x, C.w};
#pragma unroll
    for (int t = 0; t < 4; ++t) {
      float dx = px[t] - qx, dy = py[t] - qy, dz = pz[t] - qz;
      float d2 = dx * dx + dy * dy + dz * dz;
      if (d2 <= 0.04f) {
        int pos = atomicAdd(&cnt_s, 1);
        if (pos < M_MAX)
          keys[pos] = ((unsigned long long)__float_as_uint(d2) << 32) | (unsigned)(gp * 4 + t);
        int b = min((int)(d2 * 6400.0f), 255);
        atomicAdd(&hist32[b], 1);
        if (d2 <= 0.01f) atomicAdd(&hist16[min(b, 63)], 1);
      }
    }
  }
  __syncthreads();
  const int cnt = min(cnt_s, M_MAX);

  {
    int v = hist32[tid];
#pragma unroll
    for (int o = 1; o < 64; o <<= 1) {
      int t = __shfl_up(v, o, 64);
      if (lane >= o) v += t;
    }
    if (lane == 63) wsum[wv] = v;
    int v16 = 0;
    if (wv == 0) {
      v16 = hist16[lane];
#pragma unroll
      for (int o = 1; o < 64; o <<= 1) {
        int t = __shfl_up(v16, o, 64);
        if (lane >= o) v16 += t;
      }
    }
    __syncthreads();
    int off = 0;
    for (int w = 0; w < wv; ++w) off += wsum[w];
    hist32[tid] = v + off;
    if (wv == 0) hist16[lane] = v16;
    __syncthreads();
  }

  const int k32 = min(32, cnt);
  const int c16tot = hist16[63];
  const int k16 = min(16, c16tot);

  {
    int c = hist32[tid], cp = tid ? hist32[tid - 1] : 0;
    if (k32 > 0 && c >= k32 && cp < k32) { bbin[1] = tid; msel[1] = k32 - cp; }
    if (tid < 64) {
      int c6 = hist16[tid], cp6 = tid ? hist16[tid - 1] : 0;
      if (k16 > 0 && c6 >= k16 && cp6 < k16) { bbin[0] = tid; msel[0] = k16 - cp6; }
    }
  }
  __syncthreads();

  const int b32b = (k32 > 0) ? bbin[1] : -1;
  const int b16b = (k16 > 0) ? bbin[0] : -1;
  for (int i = tid; i < cnt; i += 256) {
    unsigned long long key = keys[i];
    float d2 = __uint_as_float((unsigned)(key >> 32));
    int b = min((int)(d2 * 6400.0f), 255);
    if (b == b32b) { int p = atomicAdd(&tmpcnt[1], 1); if (p < FTMP_CAP) tmpb[1][p] = key; }
    if (d2 <= 0.01f && min(b, 63) == b16b) {
      int p = atomicAdd(&tmpcnt[0], 1); if (p < FTMP_CAP) tmpb[0][p] = key;
    }
  }
  __syncthreads();

  if (wv < 2) {
    const int s = 1 - wv;
    const int k = s ? k32 : k16;
    if (k > 0) {
      const int h = min(tmpcnt[s], FTMP_CAP);
      const int m = msel[s];
      for (int base = 0; base < h; base += 64) {
        int ii = base + lane;
        if (ii < h) {
          unsigned long long e = tmpb[s][ii];
          int less = 0;
          for (int j = 0; j < h; ++j) less += (tmpb[s][j] < e) ? 1 : 0;
          if (less == m - 1) T_lds[s] = e;
        }
      }
    }
  }
  __syncthreads();

  {
    const unsigned long long T32 = (k32 > 0) ? T_lds[1] : 0ULL;
    const unsigned long long T16 = T_lds[0];
    for (int i = tid; i < cnt; i += 256) {
      unsigned long long key = keys[i];
      if (k32 > 0 && key <= T32) {
        float d2 = __uint_as_float((unsigned)(key >> 32));
        int idx = (int)(key & 0xffffffffu);
        float rx = ppts[idx * 3 + 0] - qx;
        float ry = ppts[idx * 3 + 1] - qy;
        float rz = ppts[idx * 3 + 2] - qz;
        bool f16 = (k16 > 0) && (d2 <= 0.01f) && (key <= T16);
        int slot = atomicAdd(&selcnt, 1);
        if (slot < 32) sel[slot] = make_float4(rx, ry, rz, f16 ? 1.0f : 0.0f);
      }
    }
  }
  __syncthreads();

  {
    const int nsel = min(selcnt, 32);
    const int scale = tid >> 7;
    const int h = tid & 127;
    const float w0 = W1[(scale * 3 + 0) * 128 + h];
    const float w1 = W1[(scale * 3 + 1) * 128 + h];
    const float w2 = W1[(scale * 3 + 2) * 128 + h];
    const float bb = b1[scale * 128 + h];
    float maxv = -INFINITY;
    for (int j = 0; j < nsel; ++j) {
      float4 e = sel[j];
      float val = e.x * w0 + e.y * w1 + e.z * w2;
      bool ok = scale ? true : (e.w > 0.5f);
      maxv = ok ? fmaxf(maxv, val) : maxv;
    }
    f_lds[tid] = fmaxf(maxv + bb, 0.0f);
  }
  __syncthreads();

  float* part = (float*)keys;
  {
    float4 acc = make_float4(0.f, 0.f, 0.f, 0.f);
    for (int r = 0; r < 64; ++r) {
      float fv = f_lds[wv * 64 + r];
      float4 w = ((const float4*)W2)[(wv * 64 + r) * 64 + lane];
      acc.x += fv * w.x; acc.y += fv * w.y; acc.z += fv * w.z; acc.w += fv * w.w;
    }
    ((float4*)part)[wv * 64 + lane] = acc;
  }
  __syncthreads();
  {
    float sum = part[0 * 256 + tid] + part[1 * 256 + tid] + part[2 * 256 + tid] +
                part[3 * 256 + tid] + b2[tid];
    out[q * 256 + tid] += sum;
  }
}

// ============================ launch ============================
extern "C" void kernel_launch(void* const* d_in, const int* in_sizes, int n_in,
                              void* d_out, int out_size, void* d_ws, size_t ws_size,
                              hipStream_t stream) {
  const float* g      = (const float*)d_in[0];
  const float* s      = (const float*)d_in[1];
  const float* v      = (const float*)d_in[2];
  const float* geo_t  = (const float*)d_in[3];
  const float* surf_t = (const float*)d_in[4];
  const float* vol_t  = (const float*)d_in[5];
  const float* W1     = (const float*)d_in[6];
  const float* b1     = (const float*)d_in[7];
  const float* W2     = (const float*)d_in[8];
  const float* b2     = (const float*)d_in[9];
  float* out = (float*)d_out;

  const int NG = 4096, NS = 4096, NV = 8192;
  float* out_g = out;
  float* out_s = out + NG * 256;
  float* out_v = out + (NG + NS) * 256;

  // stack ids: 0:g<-g 1:s<-s 2:v<-v 3:g<-s 4:g<-v 5:s<-g 6:v<-g
  const int stackid[7] = {2, 4, 6, 0, 3, 1, 5};
  const float* qp[7]   = {v, g, v, g, g, s, s};
  const int    nq[7]   = {NV, NG, NV, NG, NG, NS, NS};
  const int    pset[7] = {2, 2, 0, 0, 1, 1, 0};
  const int    setbase[3] = {0, 4096, 8192};

  const size_t FB = (size_t)36864 * 256 * sizeof(unsigned short);
  const size_t WT = (size_t)7 * 256 * 256 * sizeof(unsigned short);
  const size_t GI = (size_t)3 * NBIN * sizeof(int);
  const size_t need = FB + WT + GI + (size_t)16384 * sizeof(float4);

  if (ws_size >= need) {
    unsigned short* fbuf = (unsigned short*)d_ws;
    unsigned short* W2F  = (unsigned short*)((char*)d_ws + FB);
    int* starts = (int*)((char*)d_ws + FB + WT);
    float4* binned = (float4*)((char*)d_ws + FB + WT + GI);

    hipLaunchKernelGGL(prep_kernel, dim3(227), dim3(256), 0, stream,
                       g, s, v, W2, W2F, starts, binned);

    SelDesc sd;
    int blk = 0, frow = 0;
    int foffs[7];
    for (int i = 0; i < 7; ++i) {
      sd.qptr[i] = qp[i];
      sd.pbase[i] = setbase[pset[i]];
      sd.soff[i] = pset[i] * NBIN;
      sd.w1off[i] = stackid[i] * 768;
      sd.b1off[i] = stackid[i] * 256;
      sd.foff[i] = frow;
      // phase-1 radius tuned so E[candidates] ~ 52 (dense vol set vs 4k sets)
      sd.r1[i] = (pset[i] == 2) ? 0.115f : 0.145f;
      foffs[i] = frow;
      sd.blkstart[i] = blk;
      blk += nq[i] / 4;
      frow += nq[i];
    }
    sd.blkstart[7] = blk;
    hipLaunchKernelGGL(bq_select_grid, dim3(blk), dim3(256), 0, stream,
                       sd, W1, b1, binned, starts, fbuf);

    GemmDesc gd;
    gd.basep[0] = geo_t;  gd.outp[0] = out_g;
    gd.basep[1] = surf_t; gd.outp[1] = out_s;
    gd.basep[2] = vol_t;  gd.outp[2] = out_v;
    gd.blkstart[0] = 0;
    gd.blkstart[1] = NG / 32;
    gd.blkstart[2] = NG / 32 + NS / 32;
    gd.blkstart[3] = NG / 32 + NS / 32 + NV / 32;
    gd.nst[0] = 3; gd.nst[1] = 2; gd.nst[2] = 2;
    // geo: positions 1(g<-v),3(g<-g),4(g<-s); surf: 5(s<-s),6(s<-g); vol: 0(v<-v),2(v<-g)
    const int ridx[3][3] = {{1, 3, 4}, {5, 6, -1}, {0, 2, -1}};
    for (int r = 0; r < 3; ++r)
      for (int t = 0; t < gd.nst[r]; ++t) {
        int i = ridx[r][t];
        gd.foff[r][t] = foffs[i];
        gd.w2off[r][t] = stackid[i] * 256 * 256;
        gd.b2off[r][t] = stackid[i] * 256;
      }
    hipLaunchKernelGGL(bq_gemm_mfma, dim3(gd.blkstart[3]), dim3(256), 0, stream,
                       gd, W2F, b2, fbuf);
  } else {
    const int total = (NG + NS + NV) * 256;
    hipLaunchKernelGGL(init_out_kernel, dim3(total / 256), dim3(256), 0, stream,
                       geo_t, surf_t, vol_t, out);
    auto launch = [&](int stack, const float* qp_, int Nq, const float* pp_, int Np, float* o) {
      hipLaunchKernelGGL(bq_stack_fused, dim3(Nq), dim3(256), 0, stream,
                         qp_, pp_, Np, W1 + stack * 768, b1 + stack * 256,
                         W2 + stack * 256 * 256, b2 + stack * 256, o);
    };
    launch(0, g, NG, g, NG, out_g);
    launch(3, g, NG, s, NS, out_g);
    launch(4, g, NG, v, NV, out_g);
    launch(1, s, NS, s, NS, out_s);
    launch(5, s, NS, g, NG, out_s);
    launch(2, v, NV, v, NV, out_v);
    launch(6, v, NV, g, NG, out_v);
  }
}

// Round 5
// 196.244 us; speedup vs baseline: 1.0218x; 1.0218x over previous
//
#include <hip/hip_runtime.h>

#define CAND_CAP 320
#define M_MAX 1024
#define FTMP_CAP 128
#define NBIN 3584   // 15^3 = 3375 cells, padded to 256*14

typedef __attribute__((ext_vector_type(8))) short bf16x8;
typedef __attribute__((ext_vector_type(4))) float f32x4;
typedef __attribute__((ext_vector_type(2))) float f32x2;

__device__ __forceinline__ unsigned short f2bf(float x) {
  unsigned u = __float_as_uint(x);
  unsigned r = (u + 0x7fffu + ((u >> 16) & 1u)) >> 16;
  return (unsigned short)r;
}

__device__ __forceinline__ int cell15(float x, float y, float z) {
  int cx = min((int)(x * 15.0f), 14);
  int cy = min((int)(y * 15.0f), 14);
  int cz = min((int)(z * 15.0f), 14);
  return (cz * 15 + cy) * 15 + cx;
}

// ---- 64-lane bitonic sort (ascending) of one 64-bit key per lane ----
__device__ __forceinline__ unsigned long long bsort64(unsigned long long key, int lane) {
#pragma unroll
  for (int k = 2; k <= 64; k <<= 1) {
#pragma unroll
    for (int j = k >> 1; j >= 1; j >>= 1) {
      unsigned long long other = __shfl_xor(key, j, 64);
      bool keepMin = (((lane & k) == 0) == ((lane & j) == 0));
      unsigned long long mn = (other < key) ? other : key;
      unsigned long long mx = (other < key) ? key : other;
      key = keepMin ? mn : mx;
    }
  }
  return key;
}

// ---- clean a bitonic 64-seq into ascending order ----
__device__ __forceinline__ unsigned long long bclean64(unsigned long long key, int lane) {
#pragma unroll
  for (int j = 32; j >= 1; j >>= 1) {
    unsigned long long other = __shfl_xor(key, j, 64);
    bool keepMin = ((lane & j) == 0);
    unsigned long long mn = (other < key) ? other : key;
    unsigned long long mx = (other < key) ? key : other;
    key = keepMin ? mn : mx;
  }
  return key;
}

// ============================ fused prep kernel ============================
__global__ __launch_bounds__(256) void prep_kernel(
    const float* __restrict__ g, const float* __restrict__ s, const float* __restrict__ v,
    const float* __restrict__ W2, unsigned short* __restrict__ W2F,
    int* __restrict__ starts, float4* __restrict__ binned) {
  const int b = blockIdx.x;
  if (b < 3) {
    __shared__ int hist[NBIN];
    __shared__ int wsum[4];
    const int tid = threadIdx.x, lane = tid & 63, wv = tid >> 6;
    const float* p = (b == 0) ? g : (b == 1) ? s : v;
    const int Np = (b == 2) ? 8192 : 4096;
    const int base = (b == 0) ? 0 : (b == 1) ? 4096 : 8192;

    for (int i = tid; i < NBIN; i += 256) hist[i] = 0;
    __syncthreads();
    for (int i = tid; i < Np; i += 256) {
      float x = p[i * 3 + 0], y = p[i * 3 + 1], z = p[i * 3 + 2];
      atomicAdd(&hist[cell15(x, y, z)], 1);
    }
    __syncthreads();
    int loc[14];
    int run = 0;
#pragma unroll
    for (int k = 0; k < 14; ++k) { loc[k] = run; run += hist[tid * 14 + k]; }
    int is = run;
#pragma unroll
    for (int o = 1; o < 64; o <<= 1) {
      int t = __shfl_up(is, o, 64);
      if (lane >= o) is += t;
    }
    if (lane == 63) wsum[wv] = is;
    __syncthreads();
    int off = is - run;
    for (int w = 0; w < wv; ++w) off += wsum[w];
#pragma unroll
    for (int k = 0; k < 14; ++k) {
      int e = off + loc[k];
      hist[tid * 14 + k] = e;
      starts[b * NBIN + tid * 14 + k] = e;
    }
    __syncthreads();
    for (int i = tid; i < Np; i += 256) {
      float x = p[i * 3 + 0], y = p[i * 3 + 1], z = p[i * 3 + 2];
      int pos = atomicAdd(&hist[cell15(x, y, z)], 1);
      binned[base + pos] = make_float4(x, y, z, __int_as_float(i));
    }
  } else {
    int t = (b - 3) * 256 + threadIdx.x;
    int s_ = t >> 13;
    int rem = t & 8191;
    int nb = rem >> 9;
    int rem2 = rem & 511;
    int kt = rem2 >> 6;
    int l = rem2 & 63;
    int n = nb * 16 + (l & 15);
    int k0 = kt * 32 + (l >> 4) * 8;
    bf16x8 vfr;
#pragma unroll
    for (int j = 0; j < 8; ++j)
      vfr[j] = (short)f2bf(W2[((size_t)s_ * 256 + (k0 + j)) * 256 + n]);
    *(bf16x8*)(W2F + (size_t)t * 8) = vfr;
  }
}

// ============================ merged select kernel ============================
struct SelDesc {
  const float* qptr[7];
  int pbase[7];
  int soff[7];
  int w1off[7];
  int b1off[7];
  int foff[7];
  float r1[7];
  int blkstart[8];
};

__global__ __launch_bounds__(256, 8) void bq_select_grid(
    SelDesc d, const float* __restrict__ W1all, const float* __restrict__ b1all,
    const float4* __restrict__ binned, const int* __restrict__ starts,
    unsigned short* __restrict__ fbuf) {
  __shared__ unsigned long long keys[4][CAND_CAP];   // 10240 B
  __shared__ float4 sel[4][32];                      // 2048 B
  __shared__ float4 sel16[4][16];                    // 1024 B  -> 13312 B total

  const int tid = threadIdx.x, lane = tid & 63, wv = tid >> 6;

  int st = 0;
  while ((int)blockIdx.x >= d.blkstart[st + 1]) ++st;
  const int qlocal = ((int)blockIdx.x - d.blkstart[st]) * 4 + wv;
  const float* qpts = d.qptr[st];
  const int pbase = d.pbase[st];
  const int soff = d.soff[st];

  const float qx = qpts[qlocal * 3 + 0];
  const float qy = qpts[qlocal * 3 + 1];
  const float qz = qpts[qlocal * 3 + 2];

  // ---- adaptive phase-1 radius: keep E[candidates]~50 near boundaries ----
  // Exactness: if count(d2 <= rr^2) >= 32 then top-32 of that set == global top-32.
  // rr >= 0.1 always => scale-0 (r=0.1) candidate set complete from phase 1.
  float rr = d.r1[st];
  {
    float inv2r = 0.5f / rr;
    float fx = (fminf(qx + rr, 1.0f) - fmaxf(qx - rr, 0.0f)) * inv2r;
    float fy = (fminf(qy + rr, 1.0f) - fmaxf(qy - rr, 0.0f)) * inv2r;
    float fz = (fminf(qz + rr, 1.0f) - fmaxf(qz - rr, 0.0f)) * inv2r;
    rr = fminf(0.2f, 1.03f * rr / cbrtf(fx * fy * fz));
  }
  float rrsq = fminf(rr * rr, 0.04f);

  int cnt = 0, c16 = 0;
  for (int phase = 0;; ++phase) {
    // ---- register row table (per-row x-chord culling), 15^3 grid ----
    int T, rs_reg, ra_reg;
    {
      const int cy0 = max(0, (int)floorf((qy - rr) * 15.0f));
      const int cy1 = min(14, (int)floorf((qy + rr) * 15.0f));
      const int cz0 = max(0, (int)floorf((qz - rr) * 15.0f));
      const int cz1 = min(14, (int)floorf((qz + rr) * 15.0f));
      const int ncy = cy1 - cy0 + 1;
      const int nrows = (cz1 - cz0 + 1) * ncy;   // <= 49 at rr=0.2
      const int magic = (ncy == 1) ? 256 : (ncy == 2) ? 128 : (ncy == 3) ? 86 :
                        (ncy == 4) ? 64  : (ncy == 5) ? 52  : (ncy == 6) ? 43 : 37;
      int len = 0, beg = 0;
      if (lane < nrows) {
        int czi = (lane * magic) >> 8;          // lane / ncy (exact, lane<64 ncy<=7)
        int cz = cz0 + czi;
        int cy = cy0 + (lane - czi * ncy);
        const float CS = 1.0f / 15.0f;
        float lo = cz * CS;
        float dz = fmaxf(fmaxf(lo - qz, qz - (lo + CS)), 0.0f);
        float loy = cy * CS;
        float dy = fmaxf(fmaxf(loy - qy, qy - (loy + CS)), 0.0f);
        float dyz2 = dz * dz + dy * dy;
        if (dyz2 <= rrsq) {
          float xr = __builtin_sqrtf(rrsq - dyz2);
          int cxlo = max(0, (int)floorf((qx - xr) * 15.0f));
          int cxhi = min(14, (int)floorf((qx + xr) * 15.0f));
          int rowb = (cz * 15 + cy) * 15;
          beg = starts[soff + rowb + cxlo];
          int end = starts[soff + rowb + cxhi + 1];
          len = end - beg;
        }
      }
      int incl = len;
#pragma unroll
      for (int o = 1; o < 64; o <<= 1) {
        int t = __shfl_up(incl, o, 64);
        if (lane >= o) incl += t;
      }
      T = __shfl(incl, 63, 64);
      rs_reg = incl - len;          // exclusive prefix; lanes >= nrows hold T
      ra_reg = beg - rs_reg;
    }

    // ---- sequential dense scan, per-chunk shuffle binary search for the row ----
    cnt = 0; c16 = 0;
    for (int jb = 0; jb < T; jb += 64) {
      int j = jb + lane;
      int r = 0;
#pragma unroll
      for (int stp = 32; stp >= 1; stp >>= 1) {
        int c = r + stp;                       // c <= 63 always
        int val = __shfl(rs_reg, c, 64);
        if (val <= j) r = c;
      }
      int slot = pbase + j + __shfl(ra_reg, r, 64);
      float4 P = make_float4(1e30f, 1e30f, 0.0f, 0.0f);
      if (j < T) P = binned[slot];
      float dx = P.x - qx, dyy = P.y - qy, dzz = P.z - qz;
      float d2 = dx * dx + dyy * dyy + dzz * dzz;
      bool pred = (j < T) && (d2 <= rrsq);
      unsigned long long mask = __ballot(pred);
      if (pred) {
        int mypos = cnt + __popcll(mask & ((1ull << lane) - 1ull));
        if (mypos < CAND_CAP)
          keys[wv][mypos] = ((unsigned long long)__float_as_uint(d2) << 32) |
                            (unsigned)slot;
      }
      cnt += __popcll(mask);
      c16 += __popcll(__ballot(pred && (d2 <= 0.01f)));   // rrsq>=0.01 so complete
    }
    if (cnt >= 32 || phase == 1 || rr >= 0.2f) break;
    rr = 0.2f; rrsq = 0.04f;   // rare retry (~0.5%): sparse neighborhood
  }
  __builtin_amdgcn_wave_barrier();
  __threadfence_block();
  const int cntf = min(cnt, CAND_CAP);

  // ---- wave bitonic top-64: sorted ascending by (d2, slot) key ----
  unsigned long long key = (lane < cntf) ? keys[wv][lane] : 0xFFFFFFFFFFFFFFFFull;
  key = bsort64(key, lane);
  for (int base = 64; base < cntf; base += 64) {     // rare (~2%): merge next chunk
    unsigned long long k2 =
        (base + lane < cntf) ? keys[wv][base + lane] : 0xFFFFFFFFFFFFFFFFull;
    k2 = bsort64(k2, lane);
    unsigned long long rev = __shfl(k2, 63 - lane, 64);   // descending
    key = (rev < key) ? rev : key;                        // lowest-64 (bitonic)
    key = bclean64(key, lane);
  }

  // sorted ascending => first min(32,cnt) lanes are the 32 nearest;
  // all d2<=0.01 keys sort first => first min(16,c16) lanes are scale-0's set.
  const int nsel = min(cnt, 32);
  const int n16 = min(c16, 16);
  if (lane < nsel) {
    float4 P = binned[(unsigned)(key & 0xffffffffu)];
    float rx = P.x - qx;
    float ry = P.y - qy;
    float rz = P.z - qz;
    sel[wv][lane] = make_float4(rx, ry, rz, 0.0f);
    if (lane < n16) sel16[wv][lane] = make_float4(rx, ry, rz, 0.0f);
  }
  __builtin_amdgcn_wave_barrier();
  __threadfence_block();

  // ---- dual max-pool, 2-neighbor unroll (fmax(fmax) -> v_max3) ----
  {
    const float* W1 = W1all + d.w1off[st];
    const float* b1 = b1all + d.b1off[st];
    const int c0 = lane * 2;
    const f32x2 wx0 = *(const f32x2*)(W1 + 0 * 128 + c0);
    const f32x2 wy0 = *(const f32x2*)(W1 + 1 * 128 + c0);
    const f32x2 wz0 = *(const f32x2*)(W1 + 2 * 128 + c0);
    const f32x2 wx1 = *(const f32x2*)(W1 + 384 + 0 * 128 + c0);
    const f32x2 wy1 = *(const f32x2*)(W1 + 384 + 1 * 128 + c0);
    const f32x2 wz1 = *(const f32x2*)(W1 + 384 + 2 * 128 + c0);
    const f32x2 bb0 = *(const f32x2*)(b1 + c0);
    const f32x2 bb1 = *(const f32x2*)(b1 + 128 + c0);
    f32x2 m0; m0.x = -INFINITY; m0.y = -INFINITY;
    f32x2 m1 = m0;
    int n = 0;
    for (; n + 2 <= n16; n += 2) {
      float4 e0 = sel16[wv][n];
      float4 e1 = sel16[wv][n + 1];
      f32x2 v0 = e0.x * wx0 + e0.y * wy0 + e0.z * wz0;
      f32x2 v1 = e1.x * wx0 + e1.y * wy0 + e1.z * wz0;
      m0.x = fmaxf(m0.x, fmaxf(v0.x, v1.x));
      m0.y = fmaxf(m0.y, fmaxf(v0.y, v1.y));
    }
    if (n < n16) {
      float4 e = sel16[wv][n];
      f32x2 v = e.x * wx0 + e.y * wy0 + e.z * wz0;
      m0.x = fmaxf(m0.x, v.x);
      m0.y = fmaxf(m0.y, v.y);
    }
    n = 0;
    for (; n + 2 <= nsel; n += 2) {
      float4 e0 = sel[wv][n];
      float4 e1 = sel[wv][n + 1];
      f32x2 v0 = e0.x * wx1 + e0.y * wy1 + e0.z * wz1;
      f32x2 v1 = e1.x * wx1 + e1.y * wy1 + e1.z * wz1;
      m1.x = fmaxf(m1.x, fmaxf(v0.x, v1.x));
      m1.y = fmaxf(m1.y, fmaxf(v0.y, v1.y));
    }
    if (n < nsel) {
      float4 e = sel[wv][n];
      f32x2 v = e.x * wx1 + e.y * wy1 + e.z * wz1;
      m1.x = fmaxf(m1.x, v.x);
      m1.y = fmaxf(m1.y, v.y);
    }
    ushort2 o0, o1;
    o0.x = f2bf(fmaxf(m0.x + bb0.x, 0.0f));
    o0.y = f2bf(fmaxf(m0.y + bb0.y, 0.0f));
    o1.x = f2bf(fmaxf(m1.x + bb1.x, 0.0f));
    o1.y = f2bf(fmaxf(m1.y + bb1.y, 0.0f));
    unsigned short* fr = fbuf + (size_t)(d.foff[st] + qlocal) * 256;
    *(ushort2*)(fr + c0) = o0;
    *(ushort2*)(fr + 128 + c0) = o1;
  }
}

// ============================ MFMA GEMM kernel ============================
struct GemmDesc {
  const float* basep[3];
  float* outp[3];
  int blkstart[4];
  int nst[3];
  int foff[3][3];
  int w2off[3][3];
  int b2off[3][3];
};

// M=16 tile (1024 blocks -> 4 blocks/CU) + double-buffered ftile, 1 sync/stage.
__global__ __launch_bounds__(256) void bq_gemm_mfma(
    GemmDesc d, const unsigned short* __restrict__ W2F,
    const float* __restrict__ b2all, const unsigned short* __restrict__ fbuf) {
  __shared__ unsigned short ftile[2][16][264];
  const int tid = threadIdx.x, lane = tid & 63, wv = tid >> 6;

  int rg = 0;
  while ((int)blockIdx.x >= d.blkstart[rg + 1]) ++rg;
  const int qb = ((int)blockIdx.x - d.blkstart[rg]) * 16;

  f32x4 acc[4];
#pragma unroll
  for (int nt = 0; nt < 4; ++nt) acc[nt] = (f32x4)0.0f;

  const int nst = d.nst[rg];

  // prologue: stage 0 into buf 0
  {
    const unsigned short* fsrc = fbuf + (size_t)(d.foff[rg][0] + qb) * 256;
#pragma unroll
    for (int i = 0; i < 2; ++i) {
      int c = tid + 256 * i;
      int row = c >> 5, k8 = (c & 31) * 8;
      *(uint4*)&ftile[0][row][k8] = *(const uint4*)(fsrc + (size_t)row * 256 + k8);
    }
  }
  for (int s = 0; s < nst; ++s) {
    __syncthreads();   // buf[s&1] staged; prior compute on buf[(s+1)&1] done
    if (s + 1 < nst) {
      const unsigned short* fsrc = fbuf + (size_t)(d.foff[rg][s + 1] + qb) * 256;
#pragma unroll
      for (int i = 0; i < 2; ++i) {
        int c = tid + 256 * i;
        int row = c >> 5, k8 = (c & 31) * 8;
        *(uint4*)&ftile[(s + 1) & 1][row][k8] =
            *(const uint4*)(fsrc + (size_t)row * 256 + k8);
      }
    }
    const unsigned short* wbase = W2F + d.w2off[rg][s];
#pragma unroll
    for (int kt = 0; kt < 8; ++kt) {
      const int koff = kt * 32 + (lane >> 4) * 8;
      bf16x8 a0 = *(const bf16x8*)&ftile[s & 1][lane & 15][koff];
#pragma unroll
      for (int nt = 0; nt < 4; ++nt) {
        int nb = wv * 4 + nt;
        bf16x8 bfr = *(const bf16x8*)(wbase + (size_t)((nb * 8 + kt) * 64 + lane) * 8);
        acc[nt] = __builtin_amdgcn_mfma_f32_16x16x32_bf16(a0, bfr, acc[nt], 0, 0, 0);
      }
    }
  }

  float bb[4];
#pragma unroll
  for (int nt = 0; nt < 4; ++nt) {
    int c = wv * 64 + nt * 16 + (lane & 15);
    float sum = 0.0f;
    for (int s = 0; s < nst; ++s) sum += b2all[d.b2off[rg][s] + c];
    bb[nt] = sum;
  }

  const float* __restrict__ basep = d.basep[rg];
  float* __restrict__ outp = d.outp[rg];
#pragma unroll
  for (int r = 0; r < 4; ++r) {
    int q = qb + (lane >> 4) * 4 + r;
#pragma unroll
    for (int nt = 0; nt < 4; ++nt) {
      int c = wv * 64 + nt * 16 + (lane & 15);
      outp[(size_t)q * 256 + c] = basep[(size_t)q * 256 + c] + acc[nt][r] + bb[nt];
    }
  }
}

// ============================ fused fallback (tiny ws) ============================
__global__ __launch_bounds__(256) void init_out_kernel(
    const float* __restrict__ g, const float* __restrict__ s, const float* __restrict__ v,
    float* __restrict__ out) {
  const int NG = 4096 * 256, NS = 4096 * 256;
  int i = blockIdx.x * 256 + threadIdx.x;
  if (i < NG) out[i] = g[i];
  else if (i < NG + NS) out[i] = s[i - NG];
  else out[i] = v[i - NG - NS];
}

__global__ __launch_bounds__(256) void bq_stack_fused(
    const float* __restrict__ qpts,
    const float* __restrict__ ppts, int Np,
    const float* __restrict__ W1, const float* __restrict__ b1,
    const float* __restrict__ W2, const float* __restrict__ b2,
    float* __restrict__ out) {
  __shared__ unsigned long long keys[M_MAX];
  __shared__ int hist32[256];
  __shared__ int hist16[64];
  __shared__ unsigned long long tmpb[2][FTMP_CAP];
  __shared__ int tmpcnt[2];
  __shared__ float4 sel[32];
  __shared__ int selcnt;
  __shared__ float f_lds[256];
  __shared__ int cnt_s;
  __shared__ unsigned long long T_lds[2];
  __shared__ int bbin[2], msel[2];
  __shared__ int wsum[4];
  __shared__ float qsh[3];

  const int tid = threadIdx.x;
  const int lane = tid & 63;
  const int wv = tid >> 6;
  const int q = blockIdx.x;

  hist32[tid] = 0;
  if (tid < 64) hist16[tid] = 0;
  if (tid == 0) {
    cnt_s = 0; selcnt = 0; tmpcnt[0] = 0; tmpcnt[1] = 0;
    T_lds[0] = ~0ULL; T_lds[1] = ~0ULL;
    qsh[0] = qpts[q * 3 + 0]; qsh[1] = qpts[q * 3 + 1]; qsh[2] = qpts[q * 3 + 2];
  }
  __syncthreads();
  const float qx = qsh[0], qy = qsh[1], qz = qsh[2];

  const float4* pp4 = (const float4*)ppts;
  const int groups = Np >> 2;
  for (int gp = tid; gp < groups; gp += 256) {
    float4 A = pp4[gp * 3 + 0];
    float4 Bv = pp4[gp * 3 + 1];
    float4 C = pp4[gp * 3 + 2];
    float px[4] = {A.x, A.w, Bv.z, C.y};
    float py[4] = {A.y, Bv.x, Bv.w, C.z};
    float pz[4] = {A.z, Bv.y, C.x, C.w};
#pragma unroll
    for (int t = 0; t < 4; ++t) {
      float dx = px[t] - qx, dy = py[t] - qy, dz = pz[t] - qz;
      float d2 = dx * dx + dy * dy + dz * dz;
      if (d2 <= 0.04f) {
        int pos = atomicAdd(&cnt_s, 1);
        if (pos < M_MAX)
          keys[pos] = ((unsigned long long)__float_as_uint(d2) << 32) | (unsigned)(gp * 4 + t);
        int b = min((int)(d2 * 6400.0f), 255);
        atomicAdd(&hist32[b], 1);
        if (d2 <= 0.01f) atomicAdd(&hist16[min(b, 63)], 1);
      }
    }
  }
  __syncthreads();
  const int cnt = min(cnt_s, M_MAX);

  {
    int v = hist32[tid];
#pragma unroll
    for (int o = 1; o < 64; o <<= 1) {
      int t = __shfl_up(v, o, 64);
      if (lane >= o) v += t;
    }
    if (lane == 63) wsum[wv] = v;
    int v16 = 0;
    if (wv == 0) {
      v16 = hist16[lane];
#pragma unroll
      for (int o = 1; o < 64; o <<= 1) {
        int t = __shfl_up(v16, o, 64);
        if (lane >= o) v16 += t;
      }
    }
    __syncthreads();
    int off = 0;
    for (int w = 0; w < wv; ++w) off += wsum[w];
    hist32[tid] = v + off;
    if (wv == 0) hist16[lane] = v16;
    __syncthreads();
  }

  const int k32 = min(32, cnt);
  const int c16tot = hist16[63];
  const int k16 = min(16, c16tot);

  {
    int c = hist32[tid], cp = tid ? hist32[tid - 1] : 0;
    if (k32 > 0 && c >= k32 && cp < k32) { bbin[1] = tid; msel[1] = k32 - cp; }
    if (tid < 64) {
      int c6 = hist16[tid], cp6 = tid ? hist16[tid - 1] : 0;
      if (k16 > 0 && c6 >= k16 && cp6 < k16) { bbin[0] = tid; msel[0] = k16 - cp6; }
    }
  }
  __syncthreads();

  const int b32b = (k32 > 0) ? bbin[1] : -1;
  const int b16b = (k16 > 0) ? bbin[0] : -1;
  for (int i = tid; i < cnt; i += 256) {
    unsigned long long key = keys[i];
    float d2 = __uint_as_float((unsigned)(key >> 32));
    int b = min((int)(d2 * 6400.0f), 255);
    if (b == b32b) { int p = atomicAdd(&tmpcnt[1], 1); if (p < FTMP_CAP) tmpb[1][p] = key; }
    if (d2 <= 0.01f && min(b, 63) == b16b) {
      int p = atomicAdd(&tmpcnt[0], 1); if (p < FTMP_CAP) tmpb[0][p] = key;
    }
  }
  __syncthreads();

  if (wv < 2) {
    const int s = 1 - wv;
    const int k = s ? k32 : k16;
    if (k > 0) {
      const int h = min(tmpcnt[s], FTMP_CAP);
      const int m = msel[s];
      for (int base = 0; base < h; base += 64) {
        int ii = base + lane;
        if (ii < h) {
          unsigned long long e = tmpb[s][ii];
          int less = 0;
          for (int j = 0; j < h; ++j) less += (tmpb[s][j] < e) ? 1 : 0;
          if (less == m - 1) T_lds[s] = e;
        }
      }
    }
  }
  __syncthreads();

  {
    const unsigned long long T32 = (k32 > 0) ? T_lds[1] : 0ULL;
    const unsigned long long T16 = T_lds[0];
    for (int i = tid; i < cnt; i += 256) {
      unsigned long long key = keys[i];
      if (k32 > 0 && key <= T32) {
        float d2 = __uint_as_float((unsigned)(key >> 32));
        int idx = (int)(key & 0xffffffffu);
        float rx = ppts[idx * 3 + 0] - qx;
        float ry = ppts[idx * 3 + 1] - qy;
        float rz = ppts[idx * 3 + 2] - qz;
        bool f16 = (k16 > 0) && (d2 <= 0.01f) && (key <= T16);
        int slot = atomicAdd(&selcnt, 1);
        if (slot < 32) sel[slot] = make_float4(rx, ry, rz, f16 ? 1.0f : 0.0f);
      }
    }
  }
  __syncthreads();

  {
    const int nsel = min(selcnt, 32);
    const int scale = tid >> 7;
    const int h = tid & 127;
    const float w0 = W1[(scale * 3 + 0) * 128 + h];
    const float w1 = W1[(scale * 3 + 1) * 128 + h];
    const float w2 = W1[(scale * 3 + 2) * 128 + h];
    const float bb = b1[scale * 128 + h];
    float maxv = -INFINITY;
    for (int j = 0; j < nsel; ++j) {
      float4 e = sel[j];
      float val = e.x * w0 + e.y * w1 + e.z * w2;
      bool ok = scale ? true : (e.w > 0.5f);
      maxv = ok ? fmaxf(maxv, val) : maxv;
    }
    f_lds[tid] = fmaxf(maxv + bb, 0.0f);
  }
  __syncthreads();

  float* part = (float*)keys;
  {
    float4 acc = make_float4(0.f, 0.f, 0.f, 0.f);
    for (int r = 0; r < 64; ++r) {
      float fv = f_lds[wv * 64 + r];
      float4 w = ((const float4*)W2)[(wv * 64 + r) * 64 + lane];
      acc.x += fv * w.x; acc.y += fv * w.y; acc.z += fv * w.z; acc.w += fv * w.w;
    }
    ((float4*)part)[wv * 64 + lane] = acc;
  }
  __syncthreads();
  {
    float sum = part[0 * 256 + tid] + part[1 * 256 + tid] + part[2 * 256 + tid] +
                part[3 * 256 + tid] + b2[tid];
    out[q * 256 + tid] += sum;
  }
}

// ============================ launch ============================
extern "C" void kernel_launch(void* const* d_in, const int* in_sizes, int n_in,
                              void* d_out, int out_size, void* d_ws, size_t ws_size,
                              hipStream_t stream) {
  const float* g      = (const float*)d_in[0];
  const float* s      = (const float*)d_in[1];
  const float* v      = (const float*)d_in[2];
  const float* geo_t  = (const float*)d_in[3];
  const float* surf_t = (const float*)d_in[4];
  const float* vol_t  = (const float*)d_in[5];
  const float* W1     = (const float*)d_in[6];
  const float* b1     = (const float*)d_in[7];
  const float* W2     = (const float*)d_in[8];
  const float* b2     = (const float*)d_in[9];
  float* out = (float*)d_out;

  const int NG = 4096, NS = 4096, NV = 8192;
  float* out_g = out;
  float* out_s = out + NG * 256;
  float* out_v = out + (NG + NS) * 256;

  // stack ids: 0:g<-g 1:s<-s 2:v<-v 3:g<-s 4:g<-v 5:s<-g 6:v<-g
  const int stackid[7] = {2, 4, 6, 0, 3, 1, 5};
  const float* qp[7]   = {v, g, v, g, g, s, s};
  const int    nq[7]   = {NV, NG, NV, NG, NG, NS, NS};
  const int    pset[7] = {2, 2, 0, 0, 1, 1, 0};
  const int    setbase[3] = {0, 4096, 8192};

  const size_t FB = (size_t)36864 * 256 * sizeof(unsigned short);
  const size_t WT = (size_t)7 * 256 * 256 * sizeof(unsigned short);
  const size_t GI = (size_t)3 * NBIN * sizeof(int);
  const size_t need = FB + WT + GI + (size_t)16384 * sizeof(float4);

  if (ws_size >= need) {
    unsigned short* fbuf = (unsigned short*)d_ws;
    unsigned short* W2F  = (unsigned short*)((char*)d_ws + FB);
    int* starts = (int*)((char*)d_ws + FB + WT);
    float4* binned = (float4*)((char*)d_ws + FB + WT + GI);

    hipLaunchKernelGGL(prep_kernel, dim3(227), dim3(256), 0, stream,
                       g, s, v, W2, W2F, starts, binned);

    SelDesc sd;
    int blk = 0, frow = 0;
    int foffs[7];
    for (int i = 0; i < 7; ++i) {
      sd.qptr[i] = qp[i];
      sd.pbase[i] = setbase[pset[i]];
      sd.soff[i] = pset[i] * NBIN;
      sd.w1off[i] = stackid[i] * 768;
      sd.b1off[i] = stackid[i] * 256;
      sd.foff[i] = frow;
      // phase-1 radius: E[candidates] ~= 50 for both densities
      sd.r1[i] = (pset[i] == 2) ? 0.1135f : 0.1430f;
      foffs[i] = frow;
      sd.blkstart[i] = blk;
      blk += nq[i] / 4;
      frow += nq[i];
    }
    sd.blkstart[7] = blk;
    hipLaunchKernelGGL(bq_select_grid, dim3(blk), dim3(256), 0, stream,
                       sd, W1, b1, binned, starts, fbuf);

    GemmDesc gd;
    gd.basep[0] = geo_t;  gd.outp[0] = out_g;
    gd.basep[1] = surf_t; gd.outp[1] = out_s;
    gd.basep[2] = vol_t;  gd.outp[2] = out_v;
    gd.blkstart[0] = 0;
    gd.blkstart[1] = NG / 16;
    gd.blkstart[2] = NG / 16 + NS / 16;
    gd.blkstart[3] = NG / 16 + NS / 16 + NV / 16;
    gd.nst[0] = 3; gd.nst[1] = 2; gd.nst[2] = 2;
    // geo: positions 1(g<-v),3(g<-g),4(g<-s); surf: 5(s<-s),6(s<-g); vol: 0(v<-v),2(v<-g)
    const int ridx[3][3] = {{1, 3, 4}, {5, 6, -1}, {0, 2, -1}};
    for (int r = 0; r < 3; ++r)
      for (int t = 0; t < gd.nst[r]; ++t) {
        int i = ridx[r][t];
        gd.foff[r][t] = foffs[i];
        gd.w2off[r][t] = stackid[i] * 256 * 256;
        gd.b2off[r][t] = stackid[i] * 256;
      }
    hipLaunchKernelGGL(bq_gemm_mfma, dim3(gd.blkstart[3]), dim3(256), 0, stream,
                       gd, W2F, b2, fbuf);
  } else {
    const int total = (NG + NS + NV) * 256;
    hipLaunchKernelGGL(init_out_kernel, dim3(total / 256), dim3(256), 0, stream,
                       geo_t, surf_t, vol_t, out);
    auto launch = [&](int stack, const float* qp_, int Nq, const float* pp_, int Np, float* o) {
      hipLaunchKernelGGL(bq_stack_fused, dim3(Nq), dim3(256), 0, stream,
                         qp_, pp_, Np, W1 + stack * 768, b1 + stack * 256,
                         W2 + stack * 256 * 256, b2 + stack * 256, o);
    };
    launch(0, g, NG, g, NG, out_g);
    launch(3, g, NG, s, NS, out_g);
    launch(4, g, NG, v, NV, out_g);
    launch(1, s, NS, s, NS, out_s);
    launch(5, s, NS, g, NG, out_s);
    launch(2, v, NV, v, NV, out_v);
    launch(6, v, NV, g, NG, out_v);
  }
}

// Round 6
// 186.467 us; speedup vs baseline: 1.0754x; 1.0524x over previous
//
#include <hip/hip_runtime.h>

#define CAND_CAP 320
#define TMP_CAP 64
#define M_MAX 1024
#define FTMP_CAP 128
#define NBIN 3584   // 15^3 = 3375 cells, padded to 256*14

typedef __attribute__((ext_vector_type(8))) short bf16x8;
typedef __attribute__((ext_vector_type(4))) float f32x4;
typedef __attribute__((ext_vector_type(2))) float f32x2;

__device__ __forceinline__ unsigned short f2bf(float x) {
  unsigned u = __float_as_uint(x);
  unsigned r = (u + 0x7fffu + ((u >> 16) & 1u)) >> 16;
  return (unsigned short)r;
}

__device__ __forceinline__ int cell15(float x, float y, float z) {
  int cx = min((int)(x * 15.0f), 14);
  int cy = min((int)(y * 15.0f), 14);
  int cz = min((int)(z * 15.0f), 14);
  return (cz * 15 + cy) * 15 + cx;
}

// ============================ fused prep kernel ============================
__global__ __launch_bounds__(256) void prep_kernel(
    const float* __restrict__ g, const float* __restrict__ s, const float* __restrict__ v,
    const float* __restrict__ W2, unsigned short* __restrict__ W2F,
    int* __restrict__ starts, float4* __restrict__ binned) {
  const int b = blockIdx.x;
  if (b < 3) {
    __shared__ int hist[NBIN];
    __shared__ int wsum[4];
    const int tid = threadIdx.x, lane = tid & 63, wv = tid >> 6;
    const float* p = (b == 0) ? g : (b == 1) ? s : v;
    const int Np = (b == 2) ? 8192 : 4096;
    const int base = (b == 0) ? 0 : (b == 1) ? 4096 : 8192;

    for (int i = tid; i < NBIN; i += 256) hist[i] = 0;
    __syncthreads();
    for (int i = tid; i < Np; i += 256) {
      float x = p[i * 3 + 0], y = p[i * 3 + 1], z = p[i * 3 + 2];
      atomicAdd(&hist[cell15(x, y, z)], 1);
    }
    __syncthreads();
    int loc[14];
    int run = 0;
#pragma unroll
    for (int k = 0; k < 14; ++k) { loc[k] = run; run += hist[tid * 14 + k]; }
    int is = run;
#pragma unroll
    for (int o = 1; o < 64; o <<= 1) {
      int t = __shfl_up(is, o, 64);
      if (lane >= o) is += t;
    }
    if (lane == 63) wsum[wv] = is;
    __syncthreads();
    int off = is - run;
    for (int w = 0; w < wv; ++w) off += wsum[w];
#pragma unroll
    for (int k = 0; k < 14; ++k) {
      int e = off + loc[k];
      hist[tid * 14 + k] = e;
      starts[b * NBIN + tid * 14 + k] = e;
    }
    __syncthreads();
    for (int i = tid; i < Np; i += 256) {
      float x = p[i * 3 + 0], y = p[i * 3 + 1], z = p[i * 3 + 2];
      int pos = atomicAdd(&hist[cell15(x, y, z)], 1);
      binned[base + pos] = make_float4(x, y, z, __int_as_float(i));
    }
  } else {
    int t = (b - 3) * 256 + threadIdx.x;
    int s_ = t >> 13;
    int rem = t & 8191;
    int nb = rem >> 9;
    int rem2 = rem & 511;
    int kt = rem2 >> 6;
    int l = rem2 & 63;
    int n = nb * 16 + (l & 15);
    int k0 = kt * 32 + (l >> 4) * 8;
    bf16x8 vfr;
#pragma unroll
    for (int j = 0; j < 8; ++j)
      vfr[j] = (short)f2bf(W2[((size_t)s_ * 256 + (k0 + j)) * 256 + n]);
    *(bf16x8*)(W2F + (size_t)t * 8) = vfr;
  }
}

// ============================ merged select kernel ============================
struct SelDesc {
  const float* qptr[7];
  int pbase[7];
  int soff[7];
  int w1off[7];
  int b1off[7];
  int foff[7];
  float r1[7];
  int blkstart[8];
};

__global__ __launch_bounds__(256, 8) void bq_select_grid(
    SelDesc d, const float* __restrict__ W1all, const float* __restrict__ b1all,
    const float4* __restrict__ binned, const int* __restrict__ starts,
    unsigned short* __restrict__ fbuf) {
  __shared__ unsigned long long keys[4][CAND_CAP];   // 10240 B
  __shared__ unsigned long long tmpb[4][2][TMP_CAP]; // 4096 B
  __shared__ unsigned long long Tkey[4][2];          // 64 B
  __shared__ int hist64[4][64];                      // 1024 B
  __shared__ int bbin[4][2];                         // 32 B
  __shared__ int msel[4][2];                         // 32 B
  __shared__ float4 sel[4][32];                      // 2048 B
  __shared__ float4 sel16[4][16];                    // 1024 B  -> 18560 B total

  const int tid = threadIdx.x, lane = tid & 63, wv = tid >> 6;

  int st = 0;
  while ((int)blockIdx.x >= d.blkstart[st + 1]) ++st;
  const int qlocal = ((int)blockIdx.x - d.blkstart[st]) * 4 + wv;
  const float* qpts = d.qptr[st];
  const int pbase = d.pbase[st];
  const int soff = d.soff[st];

  if (lane == 0) {
    Tkey[wv][0] = 0; Tkey[wv][1] = 0;
    bbin[wv][0] = -1; bbin[wv][1] = -1;
    msel[wv][0] = 0; msel[wv][1] = 0;
  }
  const float qx = qpts[qlocal * 3 + 0];
  const float qy = qpts[qlocal * 3 + 1];
  const float qz = qpts[qlocal * 3 + 2];

  // ---- adaptive phase-1 radius: keep E[candidates]~50 near boundaries ----
  // Exactness: if count(d2 <= rr^2) >= 32 then top-32 of that set == global top-32.
  // rr >= 0.1 always => scale-0 (r=0.1) candidate set complete from phase 1.
  float rr = d.r1[st];
  {
    float inv2r = 0.5f / rr;
    float fx = (fminf(qx + rr, 1.0f) - fmaxf(qx - rr, 0.0f)) * inv2r;
    float fy = (fminf(qy + rr, 1.0f) - fmaxf(qy - rr, 0.0f)) * inv2r;
    float fz = (fminf(qz + rr, 1.0f) - fmaxf(qz - rr, 0.0f)) * inv2r;
    rr = fminf(0.2f, 1.03f * rr / cbrtf(fx * fy * fz));
  }
  float rrsq = fminf(rr * rr, 0.04f);

  int cnt = 0;
  for (int phase = 0;; ++phase) {
    hist64[wv][lane] = 0;
    __builtin_amdgcn_wave_barrier();
    __threadfence_block();

    // ---- register row table (per-row x-chord culling), 15^3 grid ----
    int T, rs_reg, ra_reg;
    {
      const int cy0 = max(0, (int)floorf((qy - rr) * 15.0f));
      const int cy1 = min(14, (int)floorf((qy + rr) * 15.0f));
      const int cz0 = max(0, (int)floorf((qz - rr) * 15.0f));
      const int cz1 = min(14, (int)floorf((qz + rr) * 15.0f));
      const int ncy = cy1 - cy0 + 1;
      const int nrows = (cz1 - cz0 + 1) * ncy;   // <= 49 at rr=0.2
      const int magic = (ncy == 1) ? 256 : (ncy == 2) ? 128 : (ncy == 3) ? 86 :
                        (ncy == 4) ? 64  : (ncy == 5) ? 52  : (ncy == 6) ? 43 : 37;
      int len = 0, beg = 0;
      if (lane < nrows) {
        int czi = (lane * magic) >> 8;          // lane / ncy (exact, lane<64 ncy<=7)
        int cz = cz0 + czi;
        int cy = cy0 + (lane - czi * ncy);
        const float CS = 1.0f / 15.0f;
        float lo = cz * CS;
        float dz = fmaxf(fmaxf(lo - qz, qz - (lo + CS)), 0.0f);
        float loy = cy * CS;
        float dy = fmaxf(fmaxf(loy - qy, qy - (loy + CS)), 0.0f);
        float dyz2 = dz * dz + dy * dy;
        if (dyz2 <= rrsq) {
          float xr = __builtin_sqrtf(rrsq - dyz2);
          int cxlo = max(0, (int)floorf((qx - xr) * 15.0f));
          int cxhi = min(14, (int)floorf((qx + xr) * 15.0f));
          int rowb = (cz * 15 + cy) * 15;
          beg = starts[soff + rowb + cxlo];
          int end = starts[soff + rowb + cxhi + 1];
          len = end - beg;
        }
      }
      int incl = len;
#pragma unroll
      for (int o = 1; o < 64; o <<= 1) {
        int t = __shfl_up(incl, o, 64);
        if (lane >= o) incl += t;
      }
      T = __shfl(incl, 63, 64);
      rs_reg = incl - len;          // exclusive prefix; lanes >= nrows hold T
      ra_reg = beg - rs_reg;
    }

    // ---- sequential dense scan, per-chunk shuffle binary search for the row ----
    cnt = 0;
    for (int jb = 0; jb < T; jb += 64) {
      int j = jb + lane;
      int r = 0;
#pragma unroll
      for (int stp = 32; stp >= 1; stp >>= 1) {
        int c = r + stp;                       // c <= 63 always
        int val = __shfl(rs_reg, c, 64);
        if (val <= j) r = c;
      }
      int slot = pbase + j + __shfl(ra_reg, r, 64);
      float4 P = make_float4(1e30f, 1e30f, 0.0f, 0.0f);
      if (j < T) P = binned[slot];
      float dx = P.x - qx, dyy = P.y - qy, dzz = P.z - qz;
      float d2 = dx * dx + dyy * dyy + dzz * dzz;
      bool pred = (j < T) && (d2 <= rrsq);
      unsigned long long mask = __ballot(pred);
      if (pred) {
        int mypos = cnt + __popcll(mask & ((1ull << lane) - 1ull));
        if (mypos < CAND_CAP)
          keys[wv][mypos] = ((unsigned long long)__float_as_uint(d2) << 32) |
                            (unsigned)slot;
        atomicAdd(&hist64[wv][min((int)(d2 * 1600.0f), 63)], 1);
      }
      cnt += __popcll(mask);
    }
    if (cnt >= 32 || phase == 1 || rr >= 0.2f) break;
    rr = 0.2f; rrsq = 0.04f;   // rare retry (~0.5%): sparse neighborhood
  }
  __builtin_amdgcn_wave_barrier();
  __threadfence_block();
  const int cntf = min(cnt, CAND_CAP);
  const bool need32 = cnt > 32;

  // ---- hist64 prefix scan: c16 = exclusive prefix at bin 16 (= #d2<0.01) ----
  int c16;
  {
    int h = hist64[wv][lane];
    int incl = h;
#pragma unroll
    for (int o = 1; o < 64; o <<= 1) {
      int t = __shfl_up(incl, o, 64);
      if (lane >= o) incl += t;
    }
    int excl = incl - h;
    c16 = __shfl(excl, 16, 64);    // bins 0..15 <=> d2 < 0.01
    const bool n16b = c16 > 16;
    if (need32 && incl >= 32 && excl < 32) { bbin[wv][1] = lane; msel[wv][1] = 32 - excl; }
    if (n16b   && incl >= 16 && excl < 16) { bbin[wv][0] = lane; msel[wv][0] = 16 - excl; }
  }
  __builtin_amdgcn_wave_barrier();
  __threadfence_block();
  const int k16 = min(16, c16);
  const bool need16 = c16 > 16;
  const int b32b = bbin[wv][1];
  const int b16b = bbin[wv][0];

  // ---- collect boundary-bin keys (ballot compaction, only needed scales) ----
  int t32c = 0, t16c = 0;
  if (need32 | need16) {
    for (int base = 0; base < cntf; base += 64) {
      int i = base + lane;
      bool in = i < cntf;
      unsigned long long key = in ? keys[wv][i] : 0xFFFFFFFFFFFFFFFFull;
      float d2 = __uint_as_float((unsigned)(key >> 32));
      int bb = min((int)(d2 * 1600.0f), 63);
      if (need32) {
        bool p1 = in && (bb == b32b);
        unsigned long long m1 = __ballot(p1);
        if (p1) {
          int pos = t32c + __popcll(m1 & ((1ull << lane) - 1ull));
          if (pos < TMP_CAP) tmpb[wv][1][pos] = key;
        }
        t32c += __popcll(m1);
      }
      if (need16) {
        bool p0 = in && (bb == b16b);
        unsigned long long m0 = __ballot(p0);
        if (p0) {
          int pos = t16c + __popcll(m0 & ((1ull << lane) - 1ull));
          if (pos < TMP_CAP) tmpb[wv][0][pos] = key;
        }
        t16c += __popcll(m0);
      }
    }
  }
  __builtin_amdgcn_wave_barrier();
  __threadfence_block();

  // ---- rank-select m-th smallest key in each needed boundary bin ----
#pragma unroll
  for (int s = 0; s < 2; ++s) {
    const bool nd = s ? need32 : need16;
    if (nd) {
      const int h = min(s ? t32c : t16c, TMP_CAP);
      const int m = msel[wv][s];
      if (lane < h) {
        unsigned long long e = tmpb[wv][s][lane];
        int less = 0;
        for (int j = 0; j < h; ++j) less += (tmpb[wv][s][j] < e) ? 1 : 0;
        if (less == m - 1) Tkey[wv][s] = e;
      }
    }
  }
  __builtin_amdgcn_wave_barrier();
  __threadfence_block();
  const unsigned long long T32 =
      need32 ? Tkey[wv][1] : 0xFFFFFFFFFFFFFFFFull;
  const unsigned long long T16 =
      need16 ? Tkey[wv][0]
             : (((unsigned long long)__float_as_uint(0.01f) << 32) | 0xFFFFFFFFull);

  // ---- compact selected neighbors (ballot); coords via one binned[] load ----
  int sc = 0, sc16 = 0;
  for (int base = 0; base < cntf; base += 64) {
    int i = base + lane;
    bool in = i < cntf;
    unsigned long long key = in ? keys[wv][i] : 0xFFFFFFFFFFFFFFFFull;
    bool pred = in && (key <= T32);
    bool pred16 = in && (key <= T16);
    unsigned long long mask = __ballot(pred);
    unsigned long long mask16 = __ballot(pred16);
    unsigned long long lt = (1ull << lane) - 1ull;
    if (pred) {
      int pos = sc + __popcll(mask & lt);
      if (pos < 32) {
        float4 P = binned[key & 0xffffffffu];
        float rx = P.x - qx;
        float ry = P.y - qy;
        float rz = P.z - qz;
        sel[wv][pos] = make_float4(rx, ry, rz, 0.0f);
        if (pred16) {
          int p16 = sc16 + __popcll(mask16 & lt);
          if (p16 < 16) sel16[wv][p16] = make_float4(rx, ry, rz, 0.0f);
        }
      }
    }
    sc += __popcll(mask);
    sc16 += __popcll(mask16);
  }
  __builtin_amdgcn_wave_barrier();
  __threadfence_block();
  const int nsel = min(sc, 32);
  const int n16 = min(sc16, 16);

  // ---- dual max-pool, 2-neighbor unroll (fmax(fmax) -> v_max3) ----
  {
    const float* W1 = W1all + d.w1off[st];
    const float* b1 = b1all + d.b1off[st];
    const int c0 = lane * 2;
    const f32x2 wx0 = *(const f32x2*)(W1 + 0 * 128 + c0);
    const f32x2 wy0 = *(const f32x2*)(W1 + 1 * 128 + c0);
    const f32x2 wz0 = *(const f32x2*)(W1 + 2 * 128 + c0);
    const f32x2 wx1 = *(const f32x2*)(W1 + 384 + 0 * 128 + c0);
    const f32x2 wy1 = *(const f32x2*)(W1 + 384 + 1 * 128 + c0);
    const f32x2 wz1 = *(const f32x2*)(W1 + 384 + 2 * 128 + c0);
    const f32x2 bb0 = *(const f32x2*)(b1 + c0);
    const f32x2 bb1 = *(const f32x2*)(b1 + 128 + c0);
    f32x2 m0; m0.x = -INFINITY; m0.y = -INFINITY;
    f32x2 m1 = m0;
    int n = 0;
    for (; n + 2 <= n16; n += 2) {
      float4 e0 = sel16[wv][n];
      float4 e1 = sel16[wv][n + 1];
      f32x2 v0 = e0.x * wx0 + e0.y * wy0 + e0.z * wz0;
      f32x2 v1 = e1.x * wx0 + e1.y * wy0 + e1.z * wz0;
      m0.x = fmaxf(m0.x, fmaxf(v0.x, v1.x));
      m0.y = fmaxf(m0.y, fmaxf(v0.y, v1.y));
    }
    if (n < n16) {
      float4 e = sel16[wv][n];
      f32x2 v = e.x * wx0 + e.y * wy0 + e.z * wz0;
      m0.x = fmaxf(m0.x, v.x);
      m0.y = fmaxf(m0.y, v.y);
    }
    n = 0;
    for (; n + 2 <= nsel; n += 2) {
      float4 e0 = sel[wv][n];
      float4 e1 = sel[wv][n + 1];
      f32x2 v0 = e0.x * wx1 + e0.y * wy1 + e0.z * wz1;
      f32x2 v1 = e1.x * wx1 + e1.y * wy1 + e1.z * wz1;
      m1.x = fmaxf(m1.x, fmaxf(v0.x, v1.x));
      m1.y = fmaxf(m1.y, fmaxf(v0.y, v1.y));
    }
    if (n < nsel) {
      float4 e = sel[wv][n];
      f32x2 v = e.x * wx1 + e.y * wy1 + e.z * wz1;
      m1.x = fmaxf(m1.x, v.x);
      m1.y = fmaxf(m1.y, v.y);
    }
    ushort2 o0, o1;
    o0.x = f2bf(fmaxf(m0.x + bb0.x, 0.0f));
    o0.y = f2bf(fmaxf(m0.y + bb0.y, 0.0f));
    o1.x = f2bf(fmaxf(m1.x + bb1.x, 0.0f));
    o1.y = f2bf(fmaxf(m1.y + bb1.y, 0.0f));
    unsigned short* fr = fbuf + (size_t)(d.foff[st] + qlocal) * 256;
    *(ushort2*)(fr + c0) = o0;
    *(ushort2*)(fr + 128 + c0) = o1;
  }
}

// ============================ MFMA GEMM kernel ============================
struct GemmDesc {
  const float* basep[3];
  float* outp[3];
  int blkstart[4];
  int nst[3];
  int foff[3][3];
  int w2off[3][3];
  int b2off[3][3];
};

// M=16 tile (1024 blocks -> 4 blocks/CU) + double-buffered ftile, 1 sync/stage.
__global__ __launch_bounds__(256) void bq_gemm_mfma(
    GemmDesc d, const unsigned short* __restrict__ W2F,
    const float* __restrict__ b2all, const unsigned short* __restrict__ fbuf) {
  __shared__ unsigned short ftile[2][16][264];
  const int tid = threadIdx.x, lane = tid & 63, wv = tid >> 6;

  int rg = 0;
  while ((int)blockIdx.x >= d.blkstart[rg + 1]) ++rg;
  const int qb = ((int)blockIdx.x - d.blkstart[rg]) * 16;

  f32x4 acc[4];
#pragma unroll
  for (int nt = 0; nt < 4; ++nt) acc[nt] = (f32x4)0.0f;

  const int nst = d.nst[rg];

  // prologue: stage 0 into buf 0
  {
    const unsigned short* fsrc = fbuf + (size_t)(d.foff[rg][0] + qb) * 256;
#pragma unroll
    for (int i = 0; i < 2; ++i) {
      int c = tid + 256 * i;
      int row = c >> 5, k8 = (c & 31) * 8;
      *(uint4*)&ftile[0][row][k8] = *(const uint4*)(fsrc + (size_t)row * 256 + k8);
    }
  }
  for (int s = 0; s < nst; ++s) {
    __syncthreads();   // buf[s&1] staged; prior compute on buf[(s+1)&1] done
    if (s + 1 < nst) {
      const unsigned short* fsrc = fbuf + (size_t)(d.foff[rg][s + 1] + qb) * 256;
#pragma unroll
      for (int i = 0; i < 2; ++i) {
        int c = tid + 256 * i;
        int row = c >> 5, k8 = (c & 31) * 8;
        *(uint4*)&ftile[(s + 1) & 1][row][k8] =
            *(const uint4*)(fsrc + (size_t)row * 256 + k8);
      }
    }
    const unsigned short* wbase = W2F + d.w2off[rg][s];
#pragma unroll
    for (int kt = 0; kt < 8; ++kt) {
      const int koff = kt * 32 + (lane >> 4) * 8;
      bf16x8 a0 = *(const bf16x8*)&ftile[s & 1][lane & 15][koff];
#pragma unroll
      for (int nt = 0; nt < 4; ++nt) {
        int nb = wv * 4 + nt;
        bf16x8 bfr = *(const bf16x8*)(wbase + (size_t)((nb * 8 + kt) * 64 + lane) * 8);
        acc[nt] = __builtin_amdgcn_mfma_f32_16x16x32_bf16(a0, bfr, acc[nt], 0, 0, 0);
      }
    }
  }

  float bb[4];
#pragma unroll
  for (int nt = 0; nt < 4; ++nt) {
    int c = wv * 64 + nt * 16 + (lane & 15);
    float sum = 0.0f;
    for (int s = 0; s < nst; ++s) sum += b2all[d.b2off[rg][s] + c];
    bb[nt] = sum;
  }

  const float* __restrict__ basep = d.basep[rg];
  float* __restrict__ outp = d.outp[rg];
#pragma unroll
  for (int r = 0; r < 4; ++r) {
    int q = qb + (lane >> 4) * 4 + r;
#pragma unroll
    for (int nt = 0; nt < 4; ++nt) {
      int c = wv * 64 + nt * 16 + (lane & 15);
      outp[(size_t)q * 256 + c] = basep[(size_t)q * 256 + c] + acc[nt][r] + bb[nt];
    }
  }
}

// ============================ fused fallback (tiny ws) ============================
__global__ __launch_bounds__(256) void init_out_kernel(
    const float* __restrict__ g, const float* __restrict__ s, const float* __restrict__ v,
    float* __restrict__ out) {
  const int NG = 4096 * 256, NS = 4096 * 256;
  int i = blockIdx.x * 256 + threadIdx.x;
  if (i < NG) out[i] = g[i];
  else if (i < NG + NS) out[i] = s[i - NG];
  else out[i] = v[i - NG - NS];
}

__global__ __launch_bounds__(256) void bq_stack_fused(
    const float* __restrict__ qpts,
    const float* __restrict__ ppts, int Np,
    const float* __restrict__ W1, const float* __restrict__ b1,
    const float* __restrict__ W2, const float* __restrict__ b2,
    float* __restrict__ out) {
  __shared__ unsigned long long keys[M_MAX];
  __shared__ int hist32[256];
  __shared__ int hist16[64];
  __shared__ unsigned long long tmpb[2][FTMP_CAP];
  __shared__ int tmpcnt[2];
  __shared__ float4 sel[32];
  __shared__ int selcnt;
  __shared__ float f_lds[256];
  __shared__ int cnt_s;
  __shared__ unsigned long long T_lds[2];
  __shared__ int bbin[2], msel[2];
  __shared__ int wsum[4];
  __shared__ float qsh[3];

  const int tid = threadIdx.x;
  const int lane = tid & 63;
  const int wv = tid >> 6;
  const int q = blockIdx.x;

  hist32[tid] = 0;
  if (tid < 64) hist16[tid] = 0;
  if (tid == 0) {
    cnt_s = 0; selcnt = 0; tmpcnt[0] = 0; tmpcnt[1] = 0;
    T_lds[0] = ~0ULL; T_lds[1] = ~0ULL;
    qsh[0] = qpts[q * 3 + 0]; qsh[1] = qpts[q * 3 + 1]; qsh[2] = qpts[q * 3 + 2];
  }
  __syncthreads();
  const float qx = qsh[0], qy = qsh[1], qz = qsh[2];

  const float4* pp4 = (const float4*)ppts;
  const int groups = Np >> 2;
  for (int gp = tid; gp < groups; gp += 256) {
    float4 A = pp4[gp * 3 + 0];
    float4 Bv = pp4[gp * 3 + 1];
    float4 C = pp4[gp * 3 + 2];
    float px[4] = {A.x, A.w, Bv.z, C.y};
    float py[4] = {A.y, Bv.x, Bv.w, C.z};
    float pz[4] = {A.z, Bv.y, C.x, C.w};
#pragma unroll
    for (int t = 0; t < 4; ++t) {
      float dx = px[t] - qx, dy = py[t] - qy, dz = pz[t] - qz;
      float d2 = dx * dx + dy * dy + dz * dz;
      if (d2 <= 0.04f) {
        int pos = atomicAdd(&cnt_s, 1);
        if (pos < M_MAX)
          keys[pos] = ((unsigned long long)__float_as_uint(d2) << 32) | (unsigned)(gp * 4 + t);
        int b = min((int)(d2 * 6400.0f), 255);
        atomicAdd(&hist32[b], 1);
        if (d2 <= 0.01f) atomicAdd(&hist16[min(b, 63)], 1);
      }
    }
  }
  __syncthreads();
  const int cnt = min(cnt_s, M_MAX);

  {
    int v = hist32[tid];
#pragma unroll
    for (int o = 1; o < 64; o <<= 1) {
      int t = __shfl_up(v, o, 64);
      if (lane >= o) v += t;
    }
    if (lane == 63) wsum[wv] = v;
    int v16 = 0;
    if (wv == 0) {
      v16 = hist16[lane];
#pragma unroll
      for (int o = 1; o < 64; o <<= 1) {
        int t = __shfl_up(v16, o, 64);
        if (lane >= o) v16 += t;
      }
    }
    __syncthreads();
    int off = 0;
    for (int w = 0; w < wv; ++w) off += wsum[w];
    hist32[tid] = v + off;
    if (wv == 0) hist16[lane] = v16;
    __syncthreads();
  }

  const int k32 = min(32, cnt);
  const int c16tot = hist16[63];
  const int k16 = min(16, c16tot);

  {
    int c = hist32[tid], cp = tid ? hist32[tid - 1] : 0;
    if (k32 > 0 && c >= k32 && cp < k32) { bbin[1] = tid; msel[1] = k32 - cp; }
    if (tid < 64) {
      int c6 = hist16[tid], cp6 = tid ? hist16[tid - 1] : 0;
      if (k16 > 0 && c6 >= k16 && cp6 < k16) { bbin[0] = tid; msel[0] = k16 - cp6; }
    }
  }
  __syncthreads();

  const int b32b = (k32 > 0) ? bbin[1] : -1;
  const int b16b = (k16 > 0) ? bbin[0] : -1;
  for (int i = tid; i < cnt; i += 256) {
    unsigned long long key = keys[i];
    float d2 = __uint_as_float((unsigned)(key >> 32));
    int b = min((int)(d2 * 6400.0f), 255);
    if (b == b32b) { int p = atomicAdd(&tmpcnt[1], 1); if (p < FTMP_CAP) tmpb[1][p] = key; }
    if (d2 <= 0.01f && min(b, 63) == b16b) {
      int p = atomicAdd(&tmpcnt[0], 1); if (p < FTMP_CAP) tmpb[0][p] = key;
    }
  }
  __syncthreads();

  if (wv < 2) {
    const int s = 1 - wv;
    const int k = s ? k32 : k16;
    if (k > 0) {
      const int h = min(tmpcnt[s], FTMP_CAP);
      const int m = msel[s];
      for (int base = 0; base < h; base += 64) {
        int ii = base + lane;
        if (ii < h) {
          unsigned long long e = tmpb[s][ii];
          int less = 0;
          for (int j = 0; j < h; ++j) less += (tmpb[s][j] < e) ? 1 : 0;
          if (less == m - 1) T_lds[s] = e;
        }
      }
    }
  }
  __syncthreads();

  {
    const unsigned long long T32 = (k32 > 0) ? T_lds[1] : 0ULL;
    const unsigned long long T16 = T_lds[0];
    for (int i = tid; i < cnt; i += 256) {
      unsigned long long key = keys[i];
      if (k32 > 0 && key <= T32) {
        float d2 = __uint_as_float((unsigned)(key >> 32));
        int idx = (int)(key & 0xffffffffu);
        float rx = ppts[idx * 3 + 0] - qx;
        float ry = ppts[idx * 3 + 1] - qy;
        float rz = ppts[idx * 3 + 2] - qz;
        bool f16 = (k16 > 0) && (d2 <= 0.01f) && (key <= T16);
        int slot = atomicAdd(&selcnt, 1);
        if (slot < 32) sel[slot] = make_float4(rx, ry, rz, f16 ? 1.0f : 0.0f);
      }
    }
  }
  __syncthreads();

  {
    const int nsel = min(selcnt, 32);
    const int scale = tid >> 7;
    const int h = tid & 127;
    const float w0 = W1[(scale * 3 + 0) * 128 + h];
    const float w1 = W1[(scale * 3 + 1) * 128 + h];
    const float w2 = W1[(scale * 3 + 2) * 128 + h];
    const float bb = b1[scale * 128 + h];
    float maxv = -INFINITY;
    for (int j = 0; j < nsel; ++j) {
      float4 e = sel[j];
      float val = e.x * w0 + e.y * w1 + e.z * w2;
      bool ok = scale ? true : (e.w > 0.5f);
      maxv = ok ? fmaxf(maxv, val) : maxv;
    }
    f_lds[tid] = fmaxf(maxv + bb, 0.0f);
  }
  __syncthreads();

  float* part = (float*)keys;
  {
    float4 acc = make_float4(0.f, 0.f, 0.f, 0.f);
    for (int r = 0; r < 64; ++r) {
      float fv = f_lds[wv * 64 + r];
      float4 w = ((const float4*)W2)[(wv * 64 + r) * 64 + lane];
      acc.x += fv * w.x; acc.y += fv * w.y; acc.z += fv * w.z; acc.w += fv * w.w;
    }
    ((float4*)part)[wv * 64 + lane] = acc;
  }
  __syncthreads();
  {
    float sum = part[0 * 256 + tid] + part[1 * 256 + tid] + part[2 * 256 + tid] +
                part[3 * 256 + tid] + b2[tid];
    out[q * 256 + tid] += sum;
  }
}

// ============================ launch ============================
extern "C" void kernel_launch(void* const* d_in, const int* in_sizes, int n_in,
                              void* d_out, int out_size, void* d_ws, size_t ws_size,
                              hipStream_t stream) {
  const float* g      = (const float*)d_in[0];
  const float* s      = (const float*)d_in[1];
  const float* v      = (const float*)d_in[2];
  const float* geo_t  = (const float*)d_in[3];
  const float* surf_t = (const float*)d_in[4];
  const float* vol_t  = (const float*)d_in[5];
  const float* W1     = (const float*)d_in[6];
  const float* b1     = (const float*)d_in[7];
  const float* W2     = (const float*)d_in[8];
  const float* b2     = (const float*)d_in[9];
  float* out = (float*)d_out;

  const int NG = 4096, NS = 4096, NV = 8192;
  float* out_g = out;
  float* out_s = out + NG * 256;
  float* out_v = out + (NG + NS) * 256;

  // stack ids: 0:g<-g 1:s<-s 2:v<-v 3:g<-s 4:g<-v 5:s<-g 6:v<-g
  const int stackid[7] = {2, 4, 6, 0, 3, 1, 5};
  const float* qp[7]   = {v, g, v, g, g, s, s};
  const int    nq[7]   = {NV, NG, NV, NG, NG, NS, NS};
  const int    pset[7] = {2, 2, 0, 0, 1, 1, 0};
  const int    setbase[3] = {0, 4096, 8192};

  const size_t FB = (size_t)36864 * 256 * sizeof(unsigned short);
  const size_t WT = (size_t)7 * 256 * 256 * sizeof(unsigned short);
  const size_t GI = (size_t)3 * NBIN * sizeof(int);
  const size_t need = FB + WT + GI + (size_t)16384 * sizeof(float4);

  if (ws_size >= need) {
    unsigned short* fbuf = (unsigned short*)d_ws;
    unsigned short* W2F  = (unsigned short*)((char*)d_ws + FB);
    int* starts = (int*)((char*)d_ws + FB + WT);
    float4* binned = (float4*)((char*)d_ws + FB + WT + GI);

    hipLaunchKernelGGL(prep_kernel, dim3(227), dim3(256), 0, stream,
                       g, s, v, W2, W2F, starts, binned);

    SelDesc sd;
    int blk = 0, frow = 0;
    int foffs[7];
    for (int i = 0; i < 7; ++i) {
      sd.qptr[i] = qp[i];
      sd.pbase[i] = setbase[pset[i]];
      sd.soff[i] = pset[i] * NBIN;
      sd.w1off[i] = stackid[i] * 768;
      sd.b1off[i] = stackid[i] * 256;
      sd.foff[i] = frow;
      // phase-1 radius: E[candidates] ~= 50 for both densities
      sd.r1[i] = (pset[i] == 2) ? 0.1135f : 0.1430f;
      foffs[i] = frow;
      sd.blkstart[i] = blk;
      blk += nq[i] / 4;
      frow += nq[i];
    }
    sd.blkstart[7] = blk;
    hipLaunchKernelGGL(bq_select_grid, dim3(blk), dim3(256), 0, stream,
                       sd, W1, b1, binned, starts, fbuf);

    GemmDesc gd;
    gd.basep[0] = geo_t;  gd.outp[0] = out_g;
    gd.basep[1] = surf_t; gd.outp[1] = out_s;
    gd.basep[2] = vol_t;  gd.outp[2] = out_v;
    gd.blkstart[0] = 0;
    gd.blkstart[1] = NG / 16;
    gd.blkstart[2] = NG / 16 + NS / 16;
    gd.blkstart[3] = NG / 16 + NS / 16 + NV / 16;
    gd.nst[0] = 3; gd.nst[1] = 2; gd.nst[2] = 2;
    // geo: positions 1(g<-v),3(g<-g),4(g<-s); surf: 5(s<-s),6(s<-g); vol: 0(v<-v),2(v<-g)
    const int ridx[3][3] = {{1, 3, 4}, {5, 6, -1}, {0, 2, -1}};
    for (int r = 0; r < 3; ++r)
      for (int t = 0; t < gd.nst[r]; ++t) {
        int i = ridx[r][t];
        gd.foff[r][t] = foffs[i];
        gd.w2off[r][t] = stackid[i] * 256 * 256;
        gd.b2off[r][t] = stackid[i] * 256;
      }
    hipLaunchKernelGGL(bq_gemm_mfma, dim3(gd.blkstart[3]), dim3(256), 0, stream,
                       gd, W2F, b2, fbuf);
  } else {
    const int total = (NG + NS + NV) * 256;
    hipLaunchKernelGGL(init_out_kernel, dim3(total / 256), dim3(256), 0, stream,
                       geo_t, surf_t, vol_t, out);
    auto launch = [&](int stack, const float* qp_, int Nq, const float* pp_, int Np, float* o) {
      hipLaunchKernelGGL(bq_stack_fused, dim3(Nq), dim3(256), 0, stream,
                         qp_, pp_, Np, W1 + stack * 768, b1 + stack * 256,
                         W2 + stack * 256 * 256, b2 + stack * 256, o);
    };
    launch(0, g, NG, g, NG, out_g);
    launch(3, g, NG, s, NS, out_g);
    launch(4, g, NG, v, NV, out_g);
    launch(1, s, NS, s, NS, out_s);
    launch(5, s, NS, g, NG, out_s);
    launch(2, v, NV, v, NV, out_v);
    launch(6, v, NV, g, NG, out_v);
  }
}

// Round 7
// 184.901 us; speedup vs baseline: 1.0845x; 1.0085x over previous
//
#include <hip/hip_runtime.h>

#define CAND_CAP 320
#define TMP_CAP 64
#define M_MAX 1024
#define FTMP_CAP 128
#define NBIN 3584   // 15^3 = 3375 cells, padded to 256*14

typedef __attribute__((ext_vector_type(8))) short bf16x8;
typedef __attribute__((ext_vector_type(4))) float f32x4;
typedef __attribute__((ext_vector_type(2))) float f32x2;

__device__ __forceinline__ unsigned short f2bf(float x) {
  unsigned u = __float_as_uint(x);
  unsigned r = (u + 0x7fffu + ((u >> 16) & 1u)) >> 16;
  return (unsigned short)r;
}

__device__ __forceinline__ int cell15(float x, float y, float z) {
  int cx = min((int)(x * 15.0f), 9 + 5);
  int cy = min((int)(y * 15.0f), 14);
  int cz = min((int)(z * 15.0f), 14);
  cx = min(cx, 14);
  return (cz * 15 + cy) * 15 + cx;
}

// Intra-wave LDS ordering fence: all shared arrays in bq_select_grid are
// [wv]-sliced (single-wave access), so only LDS completion (lgkmcnt) is
// needed -- NOT the vmcnt(0) VMEM drain that __threadfence_block() emits.
__device__ __forceinline__ void lds_fence() {
  __builtin_amdgcn_wave_barrier();
  asm volatile("s_waitcnt lgkmcnt(0)" ::: "memory");
  __builtin_amdgcn_wave_barrier();
}

// ============================ fused prep kernel ============================
__global__ __launch_bounds__(256) void prep_kernel(
    const float* __restrict__ g, const float* __restrict__ s, const float* __restrict__ v,
    const float* __restrict__ W2, unsigned short* __restrict__ W2F,
    int* __restrict__ starts, float4* __restrict__ binned) {
  const int b = blockIdx.x;
  if (b < 3) {
    __shared__ int hist[NBIN];
    __shared__ int wsum[4];
    const int tid = threadIdx.x, lane = tid & 63, wv = tid >> 6;
    const float* p = (b == 0) ? g : (b == 1) ? s : v;
    const int Np = (b == 2) ? 8192 : 4096;
    const int base = (b == 0) ? 0 : (b == 1) ? 4096 : 8192;

    for (int i = tid; i < NBIN; i += 256) hist[i] = 0;
    __syncthreads();
    for (int i = tid; i < Np; i += 256) {
      float x = p[i * 3 + 0], y = p[i * 3 + 1], z = p[i * 3 + 2];
      atomicAdd(&hist[cell15(x, y, z)], 1);
    }
    __syncthreads();
    int loc[14];
    int run = 0;
#pragma unroll
    for (int k = 0; k < 14; ++k) { loc[k] = run; run += hist[tid * 14 + k]; }
    int is = run;
#pragma unroll
    for (int o = 1; o < 64; o <<= 1) {
      int t = __shfl_up(is, o, 64);
      if (lane >= o) is += t;
    }
    if (lane == 63) wsum[wv] = is;
    __syncthreads();
    int off = is - run;
    for (int w = 0; w < wv; ++w) off += wsum[w];
#pragma unroll
    for (int k = 0; k < 14; ++k) {
      int e = off + loc[k];
      hist[tid * 14 + k] = e;
      starts[b * NBIN + tid * 14 + k] = e;
    }
    __syncthreads();
    for (int i = tid; i < Np; i += 256) {
      float x = p[i * 3 + 0], y = p[i * 3 + 1], z = p[i * 3 + 2];
      int pos = atomicAdd(&hist[cell15(x, y, z)], 1);
      binned[base + pos] = make_float4(x, y, z, __int_as_float(i));
    }
  } else {
    int t = (b - 3) * 256 + threadIdx.x;
    int s_ = t >> 13;
    int rem = t & 8191;
    int nb = rem >> 9;
    int rem2 = rem & 511;
    int kt = rem2 >> 6;
    int l = rem2 & 63;
    int n = nb * 16 + (l & 15);
    int k0 = kt * 32 + (l >> 4) * 8;
    bf16x8 vfr;
#pragma unroll
    for (int j = 0; j < 8; ++j)
      vfr[j] = (short)f2bf(W2[((size_t)s_ * 256 + (k0 + j)) * 256 + n]);
    *(bf16x8*)(W2F + (size_t)t * 8) = vfr;
  }
}

// ============================ merged select kernel ============================
struct SelDesc {
  const float* qptr[7];
  int pbase[7];
  int soff[7];
  int w1off[7];
  int b1off[7];
  int foff[7];
  float r1[7];
  int blkstart[8];
};

__global__ __launch_bounds__(256, 8) void bq_select_grid(
    SelDesc d, const float* __restrict__ W1all, const float* __restrict__ b1all,
    const float4* __restrict__ binned, const int* __restrict__ starts,
    unsigned short* __restrict__ fbuf) {
  __shared__ unsigned long long keys[4][CAND_CAP];   // 10240 B
  __shared__ unsigned long long tmpb[4][2][TMP_CAP]; // 4096 B
  __shared__ unsigned long long Tkey[4][2];          // 64 B
  __shared__ int hist64[4][64];                      // 1024 B
  __shared__ int bbin[4][2];                         // 32 B
  __shared__ int msel[4][2];                         // 32 B
  __shared__ float4 sel[4][32];                      // 2048 B
  __shared__ float4 sel16[4][16];                    // 1024 B  -> 18560 B total

  const int tid = threadIdx.x, lane = tid & 63, wv = tid >> 6;
  const unsigned long long lt = (1ull << lane) - 1ull;

  int st = 0;
  while ((int)blockIdx.x >= d.blkstart[st + 1]) ++st;
  const int qlocal = ((int)blockIdx.x - d.blkstart[st]) * 4 + wv;
  const float* qpts = d.qptr[st];
  const int pbase = d.pbase[st];
  const int soff = d.soff[st];

  if (lane == 0) {
    Tkey[wv][0] = 0; Tkey[wv][1] = 0;
    bbin[wv][0] = -1; bbin[wv][1] = -1;
    msel[wv][0] = 0; msel[wv][1] = 0;
  }
  const float qx = qpts[qlocal * 3 + 0];
  const float qy = qpts[qlocal * 3 + 1];
  const float qz = qpts[qlocal * 3 + 2];

  // ---- adaptive phase-1 radius: keep E[candidates]~50 near boundaries ----
  // Exactness: if count(d2 <= rr^2) >= 32 then top-32 of that set == global top-32.
  // rr >= 0.1 always => scale-0 (r=0.1) candidate set complete from phase 1.
  float rr = d.r1[st];
  {
    float inv2r = 0.5f / rr;
    float fx = (fminf(qx + rr, 1.0f) - fmaxf(qx - rr, 0.0f)) * inv2r;
    float fy = (fminf(qy + rr, 1.0f) - fmaxf(qy - rr, 0.0f)) * inv2r;
    float fz = (fminf(qz + rr, 1.0f) - fmaxf(qz - rr, 0.0f)) * inv2r;
    rr = fminf(0.2f, 1.03f * rr / cbrtf(fx * fy * fz));
  }
  float rrsq = fminf(rr * rr, 0.04f);

  int cnt = 0;
  for (int phase = 0;; ++phase) {
    hist64[wv][lane] = 0;
    lds_fence();

    // ---- register row table (per-row x-chord culling), 15^3 grid ----
    int T, rs_reg, ra_reg;
    {
      const int cy0 = max(0, (int)floorf((qy - rr) * 15.0f));
      const int cy1 = min(14, (int)floorf((qy + rr) * 15.0f));
      const int cz0 = max(0, (int)floorf((qz - rr) * 15.0f));
      const int cz1 = min(14, (int)floorf((qz + rr) * 15.0f));
      const int ncy = cy1 - cy0 + 1;
      const int nrows = (cz1 - cz0 + 1) * ncy;   // <= 49 at rr=0.2
      const int magic = (ncy == 1) ? 256 : (ncy == 2) ? 128 : (ncy == 3) ? 86 :
                        (ncy == 4) ? 64  : (ncy == 5) ? 52  : (ncy == 6) ? 43 : 37;
      int len = 0, beg = 0;
      if (lane < nrows) {
        int czi = (lane * magic) >> 8;          // lane / ncy (exact, lane<64 ncy<=7)
        int cz = cz0 + czi;
        int cy = cy0 + (lane - czi * ncy);
        const float CS = 1.0f / 15.0f;
        float lo = cz * CS;
        float dz = fmaxf(fmaxf(lo - qz, qz - (lo + CS)), 0.0f);
        float loy = cy * CS;
        float dy = fmaxf(fmaxf(loy - qy, qy - (loy + CS)), 0.0f);
        float dyz2 = dz * dz + dy * dy;
        if (dyz2 <= rrsq) {
          float xr = __builtin_sqrtf(rrsq - dyz2);
          int cxlo = max(0, (int)floorf((qx - xr) * 15.0f));
          int cxhi = min(14, (int)floorf((qx + xr) * 15.0f));
          int rowb = (cz * 15 + cy) * 15;
          beg = starts[soff + rowb + cxlo];
          int end = starts[soff + rowb + cxhi + 1];
          len = end - beg;
        }
      }
      int incl = len;
#pragma unroll
      for (int o = 1; o < 64; o <<= 1) {
        int t = __shfl_up(incl, o, 64);
        if (lane >= o) incl += t;
      }
      T = __shfl(incl, 63, 64);
      rs_reg = incl - len;          // exclusive prefix; lanes >= nrows hold T
      ra_reg = beg - rs_reg;
    }

    // ---- sequential dense scan, per-chunk shuffle binary search for the row ----
    cnt = 0;
    for (int jb = 0; jb < T; jb += 64) {
      int j = jb + lane;
      int r = 0;
#pragma unroll
      for (int stp = 32; stp >= 1; stp >>= 1) {
        int c = r + stp;                       // c <= 63 always
        int val = __shfl(rs_reg, c, 64);
        if (val <= j) r = c;
      }
      int slot = pbase + j + __shfl(ra_reg, r, 64);
      float4 P = make_float4(1e30f, 1e30f, 0.0f, 0.0f);
      if (j < T) P = binned[slot];
      float dx = P.x - qx, dyy = P.y - qy, dzz = P.z - qz;
      float d2 = dx * dx + dyy * dyy + dzz * dzz;
      bool pred = (j < T) && (d2 <= rrsq);
      unsigned long long mask = __ballot(pred);
      if (pred) {
        int mypos = cnt + __popcll(mask & lt);
        if (mypos < CAND_CAP)
          keys[wv][mypos] = ((unsigned long long)__float_as_uint(d2) << 32) |
                            (unsigned)slot;
        atomicAdd(&hist64[wv][min((int)(d2 * 1600.0f), 63)], 1);
      }
      cnt += __popcll(mask);
    }
    if (cnt >= 32 || phase == 1 || rr >= 0.2f) break;
    rr = 0.2f; rrsq = 0.04f;   // rare retry (~0.5%): sparse neighborhood
  }
  lds_fence();
  const int cntf = min(cnt, CAND_CAP);
  const bool need32 = cnt > 32;

  // ---- hist64 prefix scan: c16 = exclusive prefix at bin 16 (= #d2<0.01) ----
  int c16;
  {
    int h = hist64[wv][lane];
    int incl = h;
#pragma unroll
    for (int o = 1; o < 64; o <<= 1) {
      int t = __shfl_up(incl, o, 64);
      if (lane >= o) incl += t;
    }
    int excl = incl - h;
    c16 = __shfl(excl, 16, 64);    // bins 0..15 <=> d2 < 0.01
    const bool n16b = c16 > 16;
    if (need32 && incl >= 32 && excl < 32) { bbin[wv][1] = lane; msel[wv][1] = 32 - excl; }
    if (n16b   && incl >= 16 && excl < 16) { bbin[wv][0] = lane; msel[wv][0] = 16 - excl; }
  }
  lds_fence();
  const bool need16 = c16 > 16;
  const int b32b = bbin[wv][1];
  const int b16b = bbin[wv][0];

  // ---- collect boundary-bin keys (ballot compaction, only needed scales) ----
  int t32c = 0, t16c = 0;
  if (need32 | need16) {
    for (int base = 0; base < cntf; base += 64) {
      int i = base + lane;
      bool in = i < cntf;
      unsigned long long key = in ? keys[wv][i] : 0xFFFFFFFFFFFFFFFFull;
      float d2 = __uint_as_float((unsigned)(key >> 32));
      int bb = min((int)(d2 * 1600.0f), 63);
      if (need32) {
        bool p1 = in && (bb == b32b);
        unsigned long long m1 = __ballot(p1);
        if (p1) {
          int pos = t32c + __popcll(m1 & lt);
          if (pos < TMP_CAP) tmpb[wv][1][pos] = key;
        }
        t32c += __popcll(m1);
      }
      if (need16) {
        bool p0 = in && (bb == b16b);
        unsigned long long m0 = __ballot(p0);
        if (p0) {
          int pos = t16c + __popcll(m0 & lt);
          if (pos < TMP_CAP) tmpb[wv][0][pos] = key;
        }
        t16c += __popcll(m0);
      }
    }
  }
  lds_fence();

  // ---- rank-select m-th smallest key in each needed boundary bin ----
#pragma unroll
  for (int s = 0; s < 2; ++s) {
    const bool nd = s ? need32 : need16;
    if (nd) {
      const int h = min(s ? t32c : t16c, TMP_CAP);
      const int m = msel[wv][s];
      if (lane < h) {
        unsigned long long e = tmpb[wv][s][lane];
        int less = 0;
        for (int j = 0; j < h; ++j) less += (tmpb[wv][s][j] < e) ? 1 : 0;
        if (less == m - 1) Tkey[wv][s] = e;
      }
    }
  }
  lds_fence();
  const unsigned long long T32 =
      need32 ? Tkey[wv][1] : 0xFFFFFFFFFFFFFFFFull;
  const unsigned long long T16 =
      need16 ? Tkey[wv][0]
             : (((unsigned long long)__float_as_uint(0.01f) << 32) | 0xFFFFFFFFull);

  // ---- compact selected neighbors (ballot); coords via one binned[] load ----
  int sc = 0, sc16 = 0;
  for (int base = 0; base < cntf; base += 64) {
    int i = base + lane;
    bool in = i < cntf;
    unsigned long long key = in ? keys[wv][i] : 0xFFFFFFFFFFFFFFFFull;
    bool pred = in && (key <= T32);
    bool pred16 = in && (key <= T16);
    unsigned long long mask = __ballot(pred);
    unsigned long long mask16 = __ballot(pred16);
    if (pred) {
      int pos = sc + __popcll(mask & lt);
      if (pos < 32) {
        float4 P = binned[key & 0xffffffffu];
        float rx = P.x - qx;
        float ry = P.y - qy;
        float rz = P.z - qz;
        sel[wv][pos] = make_float4(rx, ry, rz, 0.0f);
        if (pred16) {
          int p16 = sc16 + __popcll(mask16 & lt);
          if (p16 < 16) sel16[wv][p16] = make_float4(rx, ry, rz, 0.0f);
        }
      }
    }
    sc += __popcll(mask);
    sc16 += __popcll(mask16);
  }
  lds_fence();
  const int nsel = min(sc, 32);
  const int n16 = min(sc16, 16);

  // ---- dual max-pool, 2-neighbor unroll (fmax(fmax) -> v_max3) ----
  {
    const float* W1 = W1all + d.w1off[st];
    const float* b1 = b1all + d.b1off[st];
    const int c0 = lane * 2;
    const f32x2 wx0 = *(const f32x2*)(W1 + 0 * 128 + c0);
    const f32x2 wy0 = *(const f32x2*)(W1 + 1 * 128 + c0);
    const f32x2 wz0 = *(const f32x2*)(W1 + 2 * 128 + c0);
    const f32x2 wx1 = *(const f32x2*)(W1 + 384 + 0 * 128 + c0);
    const f32x2 wy1 = *(const f32x2*)(W1 + 384 + 1 * 128 + c0);
    const f32x2 wz1 = *(const f32x2*)(W1 + 384 + 2 * 128 + c0);
    const f32x2 bb0 = *(const f32x2*)(b1 + c0);
    const f32x2 bb1 = *(const f32x2*)(b1 + 128 + c0);
    f32x2 m0; m0.x = -INFINITY; m0.y = -INFINITY;
    f32x2 m1 = m0;
    int n = 0;
    for (; n + 2 <= n16; n += 2) {
      float4 e0 = sel16[wv][n];
      float4 e1 = sel16[wv][n + 1];
      f32x2 v0 = e0.x * wx0 + e0.y * wy0 + e0.z * wz0;
      f32x2 v1 = e1.x * wx0 + e1.y * wy0 + e1.z * wz0;
      m0.x = fmaxf(m0.x, fmaxf(v0.x, v1.x));
      m0.y = fmaxf(m0.y, fmaxf(v0.y, v1.y));
    }
    if (n < n16) {
      float4 e = sel16[wv][n];
      f32x2 v = e.x * wx0 + e.y * wy0 + e.z * wz0;
      m0.x = fmaxf(m0.x, v.x);
      m0.y = fmaxf(m0.y, v.y);
    }
    n = 0;
    for (; n + 2 <= nsel; n += 2) {
      float4 e0 = sel[wv][n];
      float4 e1 = sel[wv][n + 1];
      f32x2 v0 = e0.x * wx1 + e0.y * wy1 + e0.z * wz1;
      f32x2 v1 = e1.x * wx1 + e1.y * wy1 + e1.z * wz1;
      m1.x = fmaxf(m1.x, fmaxf(v0.x, v1.x));
      m1.y = fmaxf(m1.y, fmaxf(v0.y, v1.y));
    }
    if (n < nsel) {
      float4 e = sel[wv][n];
      f32x2 v = e.x * wx1 + e.y * wy1 + e.z * wz1;
      m1.x = fmaxf(m1.x, v.x);
      m1.y = fmaxf(m1.y, v.y);
    }
    ushort2 o0, o1;
    o0.x = f2bf(fmaxf(m0.x + bb0.x, 0.0f));
    o0.y = f2bf(fmaxf(m0.y + bb0.y, 0.0f));
    o1.x = f2bf(fmaxf(m1.x + bb1.x, 0.0f));
    o1.y = f2bf(fmaxf(m1.y + bb1.y, 0.0f));
    unsigned short* fr = fbuf + (size_t)(d.foff[st] + qlocal) * 256;
    *(ushort2*)(fr + c0) = o0;
    *(ushort2*)(fr + 128 + c0) = o1;
  }
}

// ============================ MFMA GEMM kernel ============================
struct GemmDesc {
  const float* basep[3];
  float* outp[3];
  int blkstart[4];
  int nst[3];
  int foff[3][3];
  int w2off[3][3];
  int b2off[3][3];
};

// M=16 tile (1024 blocks -> 4 blocks/CU) + double-buffered ftile, 1 sync/stage.
__global__ __launch_bounds__(256) void bq_gemm_mfma(
    GemmDesc d, const unsigned short* __restrict__ W2F,
    const float* __restrict__ b2all, const unsigned short* __restrict__ fbuf) {
  __shared__ unsigned short ftile[2][16][264];
  const int tid = threadIdx.x, lane = tid & 63, wv = tid >> 6;

  int rg = 0;
  while ((int)blockIdx.x >= d.blkstart[rg + 1]) ++rg;
  const int qb = ((int)blockIdx.x - d.blkstart[rg]) * 16;

  f32x4 acc[4];
#pragma unroll
  for (int nt = 0; nt < 4; ++nt) acc[nt] = (f32x4)0.0f;

  const int nst = d.nst[rg];

  // prologue: stage 0 into buf 0
  {
    const unsigned short* fsrc = fbuf + (size_t)(d.foff[rg][0] + qb) * 256;
#pragma unroll
    for (int i = 0; i < 2; ++i) {
      int c = tid + 256 * i;
      int row = c >> 5, k8 = (c & 31) * 8;
      *(uint4*)&ftile[0][row][k8] = *(const uint4*)(fsrc + (size_t)row * 256 + k8);
    }
  }
  for (int s = 0; s < nst; ++s) {
    __syncthreads();   // buf[s&1] staged; prior compute on buf[(s+1)&1] done
    if (s + 1 < nst) {
      const unsigned short* fsrc = fbuf + (size_t)(d.foff[rg][s + 1] + qb) * 256;
#pragma unroll
      for (int i = 0; i < 2; ++i) {
        int c = tid + 256 * i;
        int row = c >> 5, k8 = (c & 31) * 8;
        *(uint4*)&ftile[(s + 1) & 1][row][k8] =
            *(const uint4*)(fsrc + (size_t)row * 256 + k8);
      }
    }
    const unsigned short* wbase = W2F + d.w2off[rg][s];
#pragma unroll
    for (int kt = 0; kt < 8; ++kt) {
      const int koff = kt * 32 + (lane >> 4) * 8;
      bf16x8 a0 = *(const bf16x8*)&ftile[s & 1][lane & 15][koff];
#pragma unroll
      for (int nt = 0; nt < 4; ++nt) {
        int nb = wv * 4 + nt;
        bf16x8 bfr = *(const bf16x8*)(wbase + (size_t)((nb * 8 + kt) * 64 + lane) * 8);
        acc[nt] = __builtin_amdgcn_mfma_f32_16x16x32_bf16(a0, bfr, acc[nt], 0, 0, 0);
      }
    }
  }

  float bb[4];
#pragma unroll
  for (int nt = 0; nt < 4; ++nt) {
    int c = wv * 64 + nt * 16 + (lane & 15);
    float sum = 0.0f;
    for (int s = 0; s < nst; ++s) sum += b2all[d.b2off[rg][s] + c];
    bb[nt] = sum;
  }

  const float* __restrict__ basep = d.basep[rg];
  float* __restrict__ outp = d.outp[rg];
#pragma unroll
  for (int r = 0; r < 4; ++r) {
    int q = qb + (lane >> 4) * 4 + r;
#pragma unroll
    for (int nt = 0; nt < 4; ++nt) {
      int c = wv * 64 + nt * 16 + (lane & 15);
      outp[(size_t)q * 256 + c] = basep[(size_t)q * 256 + c] + acc[nt][r] + bb[nt];
    }
  }
}

// ============================ fused fallback (tiny ws) ============================
__global__ __launch_bounds__(256) void init_out_kernel(
    const float* __restrict__ g, const float* __restrict__ s, const float* __restrict__ v,
    float* __restrict__ out) {
  const int NG = 4096 * 256, NS = 4096 * 256;
  int i = blockIdx.x * 256 + threadIdx.x;
  if (i < NG) out[i] = g[i];
  else if (i < NG + NS) out[i] = s[i - NG];
  else out[i] = v[i - NG - NS];
}

__global__ __launch_bounds__(256) void bq_stack_fused(
    const float* __restrict__ qpts,
    const float* __restrict__ ppts, int Np,
    const float* __restrict__ W1, const float* __restrict__ b1,
    const float* __restrict__ W2, const float* __restrict__ b2,
    float* __restrict__ out) {
  __shared__ unsigned long long keys[M_MAX];
  __shared__ int hist32[256];
  __shared__ int hist16[64];
  __shared__ unsigned long long tmpb[2][FTMP_CAP];
  __shared__ int tmpcnt[2];
  __shared__ float4 sel[32];
  __shared__ int selcnt;
  __shared__ float f_lds[256];
  __shared__ int cnt_s;
  __shared__ unsigned long long T_lds[2];
  __shared__ int bbin[2], msel[2];
  __shared__ int wsum[4];
  __shared__ float qsh[3];

  const int tid = threadIdx.x;
  const int lane = tid & 63;
  const int wv = tid >> 6;
  const int q = blockIdx.x;

  hist32[tid] = 0;
  if (tid < 64) hist16[tid] = 0;
  if (tid == 0) {
    cnt_s = 0; selcnt = 0; tmpcnt[0] = 0; tmpcnt[1] = 0;
    T_lds[0] = ~0ULL; T_lds[1] = ~0ULL;
    qsh[0] = qpts[q * 3 + 0]; qsh[1] = qpts[q * 3 + 1]; qsh[2] = qpts[q * 3 + 2];
  }
  __syncthreads();
  const float qx = qsh[0], qy = qsh[1], qz = qsh[2];

  const float4* pp4 = (const float4*)ppts;
  const int groups = Np >> 2;
  for (int gp = tid; gp < groups; gp += 256) {
    float4 A = pp4[gp * 3 + 0];
    float4 Bv = pp4[gp * 3 + 1];
    float4 C = pp4[gp * 3 + 2];
    float px[4] = {A.x, A.w, Bv.z, C.y};
    float py[4] = {A.y, Bv.x, Bv.w, C.z};
    float pz[4] = {A.z, Bv.y, C.x, C.w};
#pragma unroll
    for (int t = 0; t < 4; ++t) {
      float dx = px[t] - qx, dy = py[t] - qy, dz = pz[t] - qz;
      float d2 = dx * dx + dy * dy + dz * dz;
      if (d2 <= 0.04f) {
        int pos = atomicAdd(&cnt_s, 1);
        if (pos < M_MAX)
          keys[pos] = ((unsigned long long)__float_as_uint(d2) << 32) | (unsigned)(gp * 4 + t);
        int b = min((int)(d2 * 6400.0f), 255);
        atomicAdd(&hist32[b], 1);
        if (d2 <= 0.01f) atomicAdd(&hist16[min(b, 63)], 1);
      }
    }
  }
  __syncthreads();
  const int cnt = min(cnt_s, M_MAX);

  {
    int v = hist32[tid];
#pragma unroll
    for (int o = 1; o < 64; o <<= 1) {
      int t = __shfl_up(v, o, 64);
      if (lane >= o) v += t;
    }
    if (lane == 63) wsum[wv] = v;
    int v16 = 0;
    if (wv == 0) {
      v16 = hist16[lane];
#pragma unroll
      for (int o = 1; o < 64; o <<= 1) {
        int t = __shfl_up(v16, o, 64);
        if (lane >= o) v16 += t;
      }
    }
    __syncthreads();
    int off = 0;
    for (int w = 0; w < wv; ++w) off += wsum[w];
    hist32[tid] = v + off;
    if (wv == 0) hist16[lane] = v16;
    __syncthreads();
  }

  const int k32 = min(32, cnt);
  const int c16tot = hist16[63];
  const int k16 = min(16, c16tot);

  {
    int c = hist32[tid], cp = tid ? hist32[tid - 1] : 0;
    if (k32 > 0 && c >= k32 && cp < k32) { bbin[1] = tid; msel[1] = k32 - cp; }
    if (tid < 64) {
      int c6 = hist16[tid], cp6 = tid ? hist16[tid - 1] : 0;
      if (k16 > 0 && c6 >= k16 && cp6 < k16) { bbin[0] = tid; msel[0] = k16 - cp6; }
    }
  }
  __syncthreads();

  const int b32b = (k32 > 0) ? bbin[1] : -1;
  const int b16b = (k16 > 0) ? bbin[0] : -1;
  for (int i = tid; i < cnt; i += 256) {
    unsigned long long key = keys[i];
    float d2 = __uint_as_float((unsigned)(key >> 32));
    int b = min((int)(d2 * 6400.0f), 255);
    if (b == b32b) { int p = atomicAdd(&tmpcnt[1], 1); if (p < FTMP_CAP) tmpb[1][p] = key; }
    if (d2 <= 0.01f && min(b, 63) == b16b) {
      int p = atomicAdd(&tmpcnt[0], 1); if (p < FTMP_CAP) tmpb[0][p] = key;
    }
  }
  __syncthreads();

  if (wv < 2) {
    const int s = 1 - wv;
    const int k = s ? k32 : k16;
    if (k > 0) {
      const int h = min(tmpcnt[s], FTMP_CAP);
      const int m = msel[s];
      for (int base = 0; base < h; base += 64) {
        int ii = base + lane;
        if (ii < h) {
          unsigned long long e = tmpb[s][ii];
          int less = 0;
          for (int j = 0; j < h; ++j) less += (tmpb[s][j] < e) ? 1 : 0;
          if (less == m - 1) T_lds[s] = e;
        }
      }
    }
  }
  __syncthreads();

  {
    const unsigned long long T32 = (k32 > 0) ? T_lds[1] : 0ULL;
    const unsigned long long T16 = T_lds[0];
    for (int i = tid; i < cnt; i += 256) {
      unsigned long long key = keys[i];
      if (k32 > 0 && key <= T32) {
        float d2 = __uint_as_float((unsigned)(key >> 32));
        int idx = (int)(key & 0xffffffffu);
        float rx = ppts[idx * 3 + 0] - qx;
        float ry = ppts[idx * 3 + 1] - qy;
        float rz = ppts[idx * 3 + 2] - qz;
        bool f16 = (k16 > 0) && (d2 <= 0.01f) && (key <= T16);
        int slot = atomicAdd(&selcnt, 1);
        if (slot < 32) sel[slot] = make_float4(rx, ry, rz, f16 ? 1.0f : 0.0f);
      }
    }
  }
  __syncthreads();

  {
    const int nsel = min(selcnt, 32);
    const int scale = tid >> 7;
    const int h = tid & 127;
    const float w0 = W1[(scale * 3 + 0) * 128 + h];
    const float w1 = W1[(scale * 3 + 1) * 128 + h];
    const float w2 = W1[(scale * 3 + 2) * 128 + h];
    const float bb = b1[scale * 128 + h];
    float maxv = -INFINITY;
    for (int j = 0; j < nsel; ++j) {
      float4 e = sel[j];
      float val = e.x * w0 + e.y * w1 + e.z * w2;
      bool ok = scale ? true : (e.w > 0.5f);
      maxv = ok ? fmaxf(maxv, val) : maxv;
    }
    f_lds[tid] = fmaxf(maxv + bb, 0.0f);
  }
  __syncthreads();

  float* part = (float*)keys;
  {
    float4 acc = make_float4(0.f, 0.f, 0.f, 0.f);
    for (int r = 0; r < 64; ++r) {
      float fv = f_lds[wv * 64 + r];
      float4 w = ((const float4*)W2)[(wv * 64 + r) * 64 + lane];
      acc.x += fv * w.x; acc.y += fv * w.y; acc.z += fv * w.z; acc.w += fv * w.w;
    }
    ((float4*)part)[wv * 64 + lane] = acc;
  }
  __syncthreads();
  {
    float sum = part[0 * 256 + tid] + part[1 * 256 + tid] + part[2 * 256 + tid] +
                part[3 * 256 + tid] + b2[tid];
    out[q * 256 + tid] += sum;
  }
}

// ============================ launch ============================
extern "C" void kernel_launch(void* const* d_in, const int* in_sizes, int n_in,
                              void* d_out, int out_size, void* d_ws, size_t ws_size,
                              hipStream_t stream) {
  const float* g      = (const float*)d_in[0];
  const float* s      = (const float*)d_in[1];
  const float* v      = (const float*)d_in[2];
  const float* geo_t  = (const float*)d_in[3];
  const float* surf_t = (const float*)d_in[4];
  const float* vol_t  = (const float*)d_in[5];
  const float* W1     = (const float*)d_in[6];
  const float* b1     = (const float*)d_in[7];
  const float* W2     = (const float*)d_in[8];
  const float* b2     = (const float*)d_in[9];
  float* out = (float*)d_out;

  const int NG = 4096, NS = 4096, NV = 8192;
  float* out_g = out;
  float* out_s = out + NG * 256;
  float* out_v = out + (NG + NS) * 256;

  // stack ids: 0:g<-g 1:s<-s 2:v<-v 3:g<-s 4:g<-v 5:s<-g 6:v<-g
  const int stackid[7] = {2, 4, 6, 0, 3, 1, 5};
  const float* qp[7]   = {v, g, v, g, g, s, s};
  const int    nq[7]   = {NV, NG, NV, NG, NG, NS, NS};
  const int    pset[7] = {2, 2, 0, 0, 1, 1, 0};
  const int    setbase[3] = {0, 4096, 8192};

  const size_t FB = (size_t)36864 * 256 * sizeof(unsigned short);
  const size_t WT = (size_t)7 * 256 * 256 * sizeof(unsigned short);
  const size_t GI = (size_t)3 * NBIN * sizeof(int);
  const size_t need = FB + WT + GI + (size_t)16384 * sizeof(float4);

  if (ws_size >= need) {
    unsigned short* fbuf = (unsigned short*)d_ws;
    unsigned short* W2F  = (unsigned short*)((char*)d_ws + FB);
    int* starts = (int*)((char*)d_ws + FB + WT);
    float4* binned = (float4*)((char*)d_ws + FB + WT + GI);

    hipLaunchKernelGGL(prep_kernel, dim3(227), dim3(256), 0, stream,
                       g, s, v, W2, W2F, starts, binned);

    SelDesc sd;
    int blk = 0, frow = 0;
    int foffs[7];
    for (int i = 0; i < 7; ++i) {
      sd.qptr[i] = qp[i];
      sd.pbase[i] = setbase[pset[i]];
      sd.soff[i] = pset[i] * NBIN;
      sd.w1off[i] = stackid[i] * 768;
      sd.b1off[i] = stackid[i] * 256;
      sd.foff[i] = frow;
      // phase-1 radius: E[candidates] ~= 50 for both densities
      sd.r1[i] = (pset[i] == 2) ? 0.1135f : 0.1430f;
      foffs[i] = frow;
      sd.blkstart[i] = blk;
      blk += nq[i] / 4;
      frow += nq[i];
    }
    sd.blkstart[7] = blk;
    hipLaunchKernelGGL(bq_select_grid, dim3(blk), dim3(256), 0, stream,
                       sd, W1, b1, binned, starts, fbuf);

    GemmDesc gd;
    gd.basep[0] = geo_t;  gd.outp[0] = out_g;
    gd.basep[1] = surf_t; gd.outp[1] = out_s;
    gd.basep[2] = vol_t;  gd.outp[2] = out_v;
    gd.blkstart[0] = 0;
    gd.blkstart[1] = NG / 16;
    gd.blkstart[2] = NG / 16 + NS / 16;
    gd.blkstart[3] = NG / 16 + NS / 16 + NV / 16;
    gd.nst[0] = 3; gd.nst[1] = 2; gd.nst[2] = 2;
    // geo: positions 1(g<-v),3(g<-g),4(g<-s); surf: 5(s<-s),6(s<-g); vol: 0(v<-v),2(v<-g)
    const int ridx[3][3] = {{1, 3, 4}, {5, 6, -1}, {0, 2, -1}};
    for (int r = 0; r < 3; ++r)
      for (int t = 0; t < gd.nst[r]; ++t) {
        int i = ridx[r][t];
        gd.foff[r][t] = foffs[i];
        gd.w2off[r][t] = stackid[i] * 256 * 256;
        gd.b2off[r][t] = stackid[i] * 256;
      }
    hipLaunchKernelGGL(bq_gemm_mfma, dim3(gd.blkstart[3]), dim3(256), 0, stream,
                       gd, W2F, b2, fbuf);
  } else {
    const int total = (NG + NS + NV) * 256;
    hipLaunchKernelGGL(init_out_kernel, dim3(total / 256), dim3(256), 0, stream,
                       geo_t, surf_t, vol_t, out);
    auto launch = [&](int stack, const float* qp_, int Nq, const float* pp_, int Np, float* o) {
      hipLaunchKernelGGL(bq_stack_fused, dim3(Nq), dim3(256), 0, stream,
                         qp_, pp_, Np, W1 + stack * 768, b1 + stack * 256,
                         W2 + stack * 256 * 256, b2 + stack * 256, o);
    };
    launch(0, g, NG, g, NG, out_g);
    launch(3, g, NG, s, NS, out_g);
    launch(4, g, NG, v, NV, out_g);
    launch(1, s, NS, s, NS, out_s);
    launch(5, s, NS, g, NG, out_s);
    launch(2, v, NV, v, NV, out_v);
    launch(6, v, NV, g, NG, out_v);
  }
}